// Round 2
// baseline (5591.988 us; speedup 1.0000x reference)
//
#include <hip/hip_runtime.h>

// Encoder: L=6 layers of (rel-pos attention + channel-LN + K=3 conv FFN + LN)
// B=4, C=256, T=1024, H=4, KC=64, FC=1024, W=10 (band |j-i|<=10), fp32 throughout.

#define Lz 6
#define Cz 256
#define FCz 1024
#define Hz 4
#define Wz 10
#define Bz 4
#define Tz 1024
#define KCz 64
#define NR 21  // 2W+1

// ---------------------------------------------------------------------------
// Pointwise GEMM: y[b,o,t] = bias[o] + sum_c w[o,c] * x[b,c,t]
// grid (T/64, O/64, B), block (16,16), each thread 4x4.
// ---------------------------------------------------------------------------
__global__ __launch_bounds__(256) void gemm_pw(
    const float* __restrict__ w, const float* __restrict__ bias,
    const float* __restrict__ x, float* __restrict__ y, int O, int Cin) {
  __shared__ float ws[16][68];  // [k][o], stride 68 for 16B-aligned reads
  __shared__ float xs[16][64];  // [k][t]
  const int tx = threadIdx.x, ty = threadIdx.y;
  const int tid = ty * 16 + tx;
  const int t0 = blockIdx.x * 64, o0 = blockIdx.y * 64, b = blockIdx.z;
  const float* xb = x + (size_t)b * Cin * Tz;
  float acc[4][4] = {};
  for (int kk = 0; kk < Cin; kk += 16) {
#pragma unroll
    for (int i = 0; i < 4; i++) {
      int id = i * 256 + tid;
      int kq = id & 15, o = id >> 4;
      ws[kq][o] = w[(size_t)(o0 + o) * Cin + kk + kq];
    }
#pragma unroll
    for (int i = 0; i < 4; i++) {
      int id = i * 256 + tid;
      int t = id & 63, kq = id >> 6;
      xs[kq][t] = xb[(size_t)(kk + kq) * Tz + t0 + t];
    }
    __syncthreads();
#pragma unroll
    for (int kq = 0; kq < 16; kq++) {
      float a[4], bv[4];
#pragma unroll
      for (int i = 0; i < 4; i++) a[i] = ws[kq][ty * 4 + i];
#pragma unroll
      for (int j = 0; j < 4; j++) bv[j] = xs[kq][tx * 4 + j];
#pragma unroll
      for (int i = 0; i < 4; i++)
#pragma unroll
        for (int j = 0; j < 4; j++) acc[i][j] += a[i] * bv[j];
    }
    __syncthreads();
  }
#pragma unroll
  for (int i = 0; i < 4; i++) {
    int o = o0 + ty * 4 + i;
    float bb = bias[o];
    float4 r = make_float4(acc[i][0] + bb, acc[i][1] + bb, acc[i][2] + bb,
                           acc[i][3] + bb);
    *(float4*)&y[((size_t)b * O + o) * Tz + t0 + tx * 4] = r;
  }
}

// ---------------------------------------------------------------------------
// FFN conv (K=3, pad 1/1) as register-blocked implicit GEMM.
// y[b,o,t] = act(bias[o] + sum_{c,k} w[o,c,k] * (x[b,c,t+k-1]*mask))
// Tile: (OB*16) outputs x 64 t per block(16,16); thread = OB x 4.
// LDS: xs[c][t] with halo (vector b128+b64 reads), wl[c*3+k][o] o-contiguous
// (rows padded to 16B-aligned stride; staging writes <=3-way bank-aliased).
// ---------------------------------------------------------------------------
template <int OB, int RELU, int OUTMASK>
__global__ __launch_bounds__(256) void conv_gemm(
    const float* __restrict__ w, const float* __restrict__ bias,
    const float* __restrict__ x, const float* __restrict__ mask,
    float* __restrict__ y, int Cout, int Cin) {
  constexpr int OT = OB * 16;       // o-tile
  constexpr int WST = OT + 4;       // wl row stride: 16B-aligned, shifts banks
  __shared__ float xs[8][72];       // [c][t0-1 .. t0+64] (66 used)
  __shared__ float wl[24][WST];     // [c*3+k][o]
  const int tx = threadIdx.x, ty = threadIdx.y;
  const int tid = ty * 16 + tx;
  const int t0 = blockIdx.x * 64, o0 = blockIdx.y * OT, b = blockIdx.z;
  const float* xb = x + (size_t)b * Cin * Tz;
  const float* mb = mask + (size_t)b * Tz;
  float acc[OB][4] = {};
  for (int cc = 0; cc < Cin; cc += 8) {
    // stage x tile with halo (coalesced; masked)
    for (int id = tid; id < 8 * 66; id += 256) {
      int u = id % 66, c = id / 66;
      int t = t0 + u - 1;
      float v = 0.f;
      if (t >= 0 && t < Tz) v = xb[(size_t)(cc + c) * Tz + t] * mb[t];
      xs[c][u] = v;
    }
    // stage weights: global runs of 24 floats per o (coalesced-ish, L2-hot)
    for (int id = tid; id < 24 * OT; id += 256) {
      int ck = id % 24, o = id / 24;
      wl[ck][o] = w[(size_t)(o0 + o) * Cin * 3 + cc * 3 + ck];
    }
    __syncthreads();
#pragma unroll
    for (int c = 0; c < 8; c++) {
      // 6 contiguous activations: b128 + b64, 16B-aligned
      const float* xp = &xs[c][tx * 4];
      float4 x4 = *(const float4*)xp;
      float2 x2 = *(const float2*)(xp + 4);
      float xv[6] = {x4.x, x4.y, x4.z, x4.w, x2.x, x2.y};
#pragma unroll
      for (int k = 0; k < 3; k++) {
        float a[OB];
        const float* ap = &wl[c * 3 + k][ty * OB];
#pragma unroll
        for (int i = 0; i < OB; i += 4) {
          float4 a4 = *(const float4*)(ap + i);
          a[i] = a4.x; a[i + 1] = a4.y; a[i + 2] = a4.z; a[i + 3] = a4.w;
        }
#pragma unroll
        for (int i = 0; i < OB; i++)
#pragma unroll
          for (int j = 0; j < 4; j++) acc[i][j] += a[i] * xv[j + k];
      }
    }
    __syncthreads();
  }
  float mk[4];
#pragma unroll
  for (int j = 0; j < 4; j++) mk[j] = OUTMASK ? mb[t0 + tx * 4 + j] : 1.f;
#pragma unroll
  for (int i = 0; i < OB; i++) {
    int o = o0 + ty * OB + i;
    float bb = bias[o];
    float r[4];
#pragma unroll
    for (int j = 0; j < 4; j++) {
      float v = acc[i][j] + bb;
      if (RELU) v = fmaxf(v, 0.f);
      if (OUTMASK) v *= mk[j];
      r[j] = v;
    }
    *(float4*)&y[((size_t)b * Cout + o) * Tz + t0 + tx * 4] =
        make_float4(r[0], r[1], r[2], r[3]);
  }
}

// ---------------------------------------------------------------------------
// Flash-style attention with banded relative-position terms.
// q,k,v,y: [B,C,T]; erk,erv: [21,64] (this layer). grid (T/64, B*H), blk 16x16.
// Thread (ty,tx) owns rows i = ty + 16*ii (ii<4), cols tx*4+jj.
// ---------------------------------------------------------------------------
__global__ __launch_bounds__(256) void attn_kernel(
    const float* __restrict__ q, const float* __restrict__ k,
    const float* __restrict__ v, const float* __restrict__ mask,
    const float* __restrict__ erk, const float* __restrict__ erv,
    float* __restrict__ y) {
  __shared__ float Qs[64][64];  // [d][i] (scaled by 1/8)
  __shared__ float SK[64][65];  // K-tile [d][j] -> P [i][j] -> O [d][i]
  __shared__ float Vs[64][65];  // [d][j]
  __shared__ float band[64][NR];  // raw masked scores on |j-i|<=10 band
  __shared__ float rq[64][NR];    // q . erk  (reused for erv at epilogue)
  __shared__ float mrow[64], lrow[64], arow[64];

  const int tx = threadIdx.x, ty = threadIdx.y;
  const int tid = ty * 16 + tx;
  const int i0 = blockIdx.x * 64;
  const int b = blockIdx.y >> 2, h = blockIdx.y & 3;
  const float* qb = q + ((size_t)b * Cz + h * KCz) * Tz;
  const float* kb = k + ((size_t)b * Cz + h * KCz) * Tz;
  const float* vb = v + ((size_t)b * Cz + h * KCz) * Tz;
  const float* mb = mask + (size_t)b * Tz;

  for (int id = tid; id < 64 * 64; id += 256) {
    int i = id & 63, d = id >> 6;
    Qs[d][i] = qb[(size_t)d * Tz + i0 + i] * 0.125f;
  }
  if (tid < 64) {
    mrow[tid] = -1e30f;
    lrow[tid] = 0.f;
  }
  for (int id = tid; id < 64 * NR; id += 256) band[id / NR][id % NR] = -1e30f;
  __syncthreads();
  // rq[i][r] = sum_d Qs[d][i] * erk[r][d]  (erk reads are L1-resident, 5 KB)
  for (int id = tid; id < 64 * NR; id += 256) {
    int i = id / NR, r = id % NR;
    float s = 0.f;
    for (int d = 0; d < KCz; d++) s += Qs[d][i] * erk[r * KCz + d];
    rq[i][r] = s;
  }

  float qmk[4];
#pragma unroll
  for (int ii = 0; ii < 4; ii++) qmk[ii] = mb[i0 + ty + 16 * ii];

  float acc[4][4] = {};

  for (int j0 = 0; j0 < Tz; j0 += 64) {
    __syncthreads();  // SK/Vs safe to overwrite; also publishes rq on iter 0
    for (int id = tid; id < 64 * 64; id += 256) {
      int j = id & 63, d = id >> 6;
      SK[d][j] = kb[(size_t)d * Tz + j0 + j];
      Vs[d][j] = vb[(size_t)d * Tz + j0 + j];
    }
    float kmk[4];
#pragma unroll
    for (int jj = 0; jj < 4; jj++) kmk[jj] = mb[j0 + tx * 4 + jj];
    __syncthreads();

    // S = (Q/sqrt(kc)) K^T
    float sc[4][4] = {};
#pragma unroll 4
    for (int d = 0; d < 64; d++) {
      float a[4], bv[4];
#pragma unroll
      for (int ii = 0; ii < 4; ii++) a[ii] = Qs[d][ty + 16 * ii];
#pragma unroll
      for (int jj = 0; jj < 4; jj++) bv[jj] = SK[d][tx * 4 + jj];
#pragma unroll
      for (int ii = 0; ii < 4; ii++)
#pragma unroll
        for (int jj = 0; jj < 4; jj++) sc[ii][jj] += a[ii] * bv[jj];
    }
    // rel-K bias (band only), mask, band capture, row-max (shfl over 16 tx)
    float mx[4];
#pragma unroll
    for (int ii = 0; ii < 4; ii++) {
      int i = ty + 16 * ii, ig = i0 + i;
      float m = -1e30f;
#pragma unroll
      for (int jj = 0; jj < 4; jj++) {
        int j = tx * 4 + jj, jg = j0 + j;
        float s = sc[ii][jj];
        int dl = jg - ig;
        if (dl >= -Wz && dl <= Wz) s += rq[i][dl + Wz];
        if (qmk[ii] * kmk[jj] == 0.f) s = -1e4f;
        sc[ii][jj] = s;
        if (dl >= -Wz && dl <= Wz) band[i][dl + Wz] = s;
        m = fmaxf(m, s);
      }
      mx[ii] = m;
    }
#pragma unroll
    for (int off = 1; off < 16; off <<= 1) {
#pragma unroll
      for (int ii = 0; ii < 4; ii++)
        mx[ii] = fmaxf(mx[ii], __shfl_xor(mx[ii], off, 16));
    }
    if (tx == 0) {
#pragma unroll
      for (int ii = 0; ii < 4; ii++) {
        int i = ty + 16 * ii;
        float nm = fmaxf(mrow[i], mx[ii]);
        float al = __expf(mrow[i] - nm);
        mrow[i] = nm;
        arow[i] = al;
        lrow[i] *= al;
      }
    }
    __syncthreads();  // mrow/arow final; K-reads of SK complete

    // P = exp(S - m) -> SK; row-sum via shfl; rescale O accumulator
    float sm[4];
#pragma unroll
    for (int ii = 0; ii < 4; ii++) {
      int i = ty + 16 * ii;
      float m = mrow[i], s = 0.f;
#pragma unroll
      for (int jj = 0; jj < 4; jj++) {
        float p = __expf(sc[ii][jj] - m);
        SK[i][tx * 4 + jj] = p;
        s += p;
      }
      sm[ii] = s;
    }
#pragma unroll
    for (int off = 1; off < 16; off <<= 1) {
#pragma unroll
      for (int ii = 0; ii < 4; ii++) sm[ii] += __shfl_xor(sm[ii], off, 16);
    }
    if (tx == 0) {
#pragma unroll
      for (int ii = 0; ii < 4; ii++) lrow[ty + 16 * ii] += sm[ii];
    }
#pragma unroll
    for (int ii = 0; ii < 4; ii++) {
      float al = arow[ty + 16 * ii];
#pragma unroll
      for (int jj = 0; jj < 4; jj++) acc[ii][jj] *= al;
    }
    __syncthreads();  // P visible

    // O += P V
#pragma unroll 4
    for (int j = 0; j < 64; j++) {
      float p[4], vv[4];
#pragma unroll
      for (int ii = 0; ii < 4; ii++) p[ii] = SK[ty + 16 * ii][j];
#pragma unroll
      for (int jj = 0; jj < 4; jj++) vv[jj] = Vs[tx * 4 + jj][j];
#pragma unroll
      for (int ii = 0; ii < 4; ii++)
#pragma unroll
        for (int jj = 0; jj < 4; jj++) acc[ii][jj] += p[ii] * vv[jj];
    }
  }

  __syncthreads();
  // epilogue: band probs + rel-V, normalize, write coalesced via SK staging
  float* ervs = &rq[0][0];  // rq no longer needed
  for (int id = tid; id < NR * KCz; id += 256) ervs[id] = erv[id];
  for (int id = tid; id < 64 * NR; id += 256) {
    int i = id / NR, r = id % NR;
    band[i][r] = __expf(band[i][r] - mrow[i]);
  }
  __syncthreads();
#pragma unroll
  for (int ii = 0; ii < 4; ii++) {
    int i = ty + 16 * ii;
    float li = 1.f / lrow[i];
    float o[4];
#pragma unroll
    for (int jj = 0; jj < 4; jj++) o[jj] = acc[ii][jj];
    for (int r = 0; r < NR; r++) {
      float pb = band[i][r];
#pragma unroll
      for (int jj = 0; jj < 4; jj++) o[jj] += pb * ervs[r * KCz + tx * 4 + jj];
    }
#pragma unroll
    for (int jj = 0; jj < 4; jj++) acc[ii][jj] = o[jj] * li;
  }
  __syncthreads();  // all PV reads of SK done (covered above), reuse as O[d][i]
#pragma unroll
  for (int ii = 0; ii < 4; ii++)
#pragma unroll
    for (int jj = 0; jj < 4; jj++)
      SK[tx * 4 + jj][ty + 16 * ii] = acc[ii][jj];
  __syncthreads();
  for (int id = tid; id < 64 * 64; id += 256) {
    int i = id & 63, d = id >> 6;
    y[((size_t)b * Cz + h * KCz + d) * Tz + i0 + i] = SK[d][i];
  }
}

// ---------------------------------------------------------------------------
// In-place residual + channel LayerNorm over C: x = LN(x + y)*g + b
// grid (T/64, B), block 256. Two passes over global (L2-resident).
// ---------------------------------------------------------------------------
__global__ __launch_bounds__(256) void add_ln(
    float* __restrict__ x, const float* __restrict__ y,
    const float* __restrict__ g, const float* __restrict__ bb) {
  __shared__ float red[8][64];
  __shared__ float ms[64], rs[64];
  const int tid = threadIdx.x;
  const int t0 = blockIdx.x * 64, b = blockIdx.y;
  const int tl = tid & 63, grp = tid >> 6;  // 4 c-groups
  const size_t base = (size_t)b * Cz * Tz + t0 + tl;
  float s = 0.f, sq = 0.f;
  for (int c = grp; c < Cz; c += 4) {
    float v = x[base + (size_t)c * Tz] + y[base + (size_t)c * Tz];
    s += v;
    sq += v * v;
  }
  red[grp][tl] = s;
  red[4 + grp][tl] = sq;
  __syncthreads();
  if (tid < 64) {
    float su = red[0][tid] + red[1][tid] + red[2][tid] + red[3][tid];
    float sqq = red[4][tid] + red[5][tid] + red[6][tid] + red[7][tid];
    float m = su * (1.f / Cz);
    float var = sqq * (1.f / Cz) - m * m;
    ms[tid] = m;
    rs[tid] = rsqrtf(var + 1e-5f);
  }
  __syncthreads();
  float m = ms[tl], r = rs[tl];
  for (int c = grp; c < Cz; c += 4) {
    float v = x[base + (size_t)c * Tz] + y[base + (size_t)c * Tz];
    x[base + (size_t)c * Tz] = (v - m) * r * g[c] + bb[c];
  }
}

__global__ __launch_bounds__(256) void mask_mul(
    const float* __restrict__ x, const float* __restrict__ mask,
    float* __restrict__ out, int n) {
  int idx = blockIdx.x * 256 + threadIdx.x;
  if (idx < n) {
    int t = idx & (Tz - 1);
    int b = idx / (Cz * Tz);
    out[idx] = x[idx] * mask[b * Tz + t];
  }
}

// ---------------------------------------------------------------------------
extern "C" void kernel_launch(void* const* d_in, const int* in_sizes, int n_in,
                              void* d_out, int out_size, void* d_ws,
                              size_t ws_size, hipStream_t stream) {
  const float* x = (const float*)d_in[0];
  const float* xm = (const float*)d_in[1];
  const float* wq = (const float*)d_in[2];
  const float* bq = (const float*)d_in[3];
  const float* wk = (const float*)d_in[4];
  const float* bk = (const float*)d_in[5];
  const float* wv = (const float*)d_in[6];
  const float* bv = (const float*)d_in[7];
  const float* wo = (const float*)d_in[8];
  const float* bo = (const float*)d_in[9];
  const float* erk = (const float*)d_in[10];
  const float* erv = (const float*)d_in[11];
  const float* g1 = (const float*)d_in[12];
  const float* b1 = (const float*)d_in[13];
  const float* fw1 = (const float*)d_in[14];
  const float* fb1 = (const float*)d_in[15];
  const float* fw2 = (const float*)d_in[16];
  const float* fb2 = (const float*)d_in[17];
  const float* g2 = (const float*)d_in[18];
  const float* b2 = (const float*)d_in[19];

  const size_t NBC = (size_t)Bz * Cz * Tz;  // 1,048,576 floats
  float* ws = (float*)d_ws;
  float* xb = ws;               // current activation
  float* yb = ws + NBC;         // residual branch
  float* qb = ws + 2 * NBC;
  float* kb2 = ws + 3 * NBC;
  float* vb2 = ws + 4 * NBC;
  float* ao = ws + 5 * NBC;
  float* hb = qb;  // FFN hidden [B,FC,T] reuses q/k/v/ao (4*NBC floats)

  dim3 blk(16, 16);
  const int ntot = (int)NBC;
  mask_mul<<<dim3((ntot + 255) / 256), dim3(256), 0, stream>>>(x, xm, xb, ntot);
  for (int l = 0; l < Lz; l++) {
    gemm_pw<<<dim3(16, 4, 4), blk, 0, stream>>>(wq + (size_t)l * Cz * Cz,
                                                bq + l * Cz, xb, qb, Cz, Cz);
    gemm_pw<<<dim3(16, 4, 4), blk, 0, stream>>>(wk + (size_t)l * Cz * Cz,
                                                bk + l * Cz, xb, kb2, Cz, Cz);
    gemm_pw<<<dim3(16, 4, 4), blk, 0, stream>>>(wv + (size_t)l * Cz * Cz,
                                                bv + l * Cz, xb, vb2, Cz, Cz);
    attn_kernel<<<dim3(16, 16), blk, 0, stream>>>(
        qb, kb2, vb2, xm, erk + l * NR * KCz, erv + l * NR * KCz, ao);
    gemm_pw<<<dim3(16, 4, 4), blk, 0, stream>>>(wo + (size_t)l * Cz * Cz,
                                                bo + l * Cz, ao, yb, Cz, Cz);
    add_ln<<<dim3(16, 4), dim3(256), 0, stream>>>(xb, yb, g1 + l * Cz,
                                                  b1 + l * Cz);
    conv_gemm<8, 1, 0><<<dim3(16, 8, 4), blk, 0, stream>>>(
        fw1 + (size_t)l * FCz * Cz * 3, fb1 + l * FCz, xb, xm, hb, FCz, Cz);
    conv_gemm<4, 0, 1><<<dim3(16, 4, 4), blk, 0, stream>>>(
        fw2 + (size_t)l * Cz * FCz * 3, fb2 + l * Cz, hb, xm, yb, Cz, FCz);
    add_ln<<<dim3(16, 4), dim3(256), 0, stream>>>(xb, yb, g2 + l * Cz,
                                                  b2 + l * Cz);
  }
  mask_mul<<<dim3((ntot + 255) / 256), dim3(256), 0, stream>>>(
      xb, xm, (float*)d_out, ntot);
}

// Round 3
// 2864.863 us; speedup vs baseline: 1.9519x; 1.9519x over previous
//
#include <hip/hip_runtime.h>

// Encoder: L=6 layers of (rel-pos attention + channel-LN + K=3 conv FFN + LN)
// B=4, C=256, T=1024, H=4, KC=64, FC=1024, W=10, fp32.
// Conv/GEMM strategy: wave-independent implicit GEMM, scalar (SMEM) weights,
// global-direct activation reads from padded rows, no LDS in hot loops.

#define Lz 6
#define Cz 256
#define FCz 1024
#define Hz 4
#define Wz 10
#define Bz 4
#define Tz 1024
#define KCz 64
#define NR 21
#define TS 1032   // padded activation row stride (front pad 4, back pad 4)
#define PADF 4

// Zero the 8 pad cells of each padded row (front 4 + back 4).
__global__ __launch_bounds__(256) void zero_pads(float* buf, int nrows) {
  int id = blockIdx.x * 256 + threadIdx.x;
  if (id < nrows * 8) {
    int r = id >> 3, p = id & 7;
    buf[(size_t)r * TS + (p < 4 ? p : 1024 + p)] = 0.f;
  }
}

// x[B,C,T] * mask -> padded xb[B,C,TS]
__global__ __launch_bounds__(256) void mask_in(const float* __restrict__ x,
                                               const float* __restrict__ m,
                                               float* __restrict__ xp) {
  int id = blockIdx.x * 256 + threadIdx.x;
  if (id < Bz * Cz * Tz) {
    int t = id & (Tz - 1), row = id >> 10, b = id >> 18;
    xp[(size_t)row * TS + PADF + t] = x[id] * m[b * Tz + t];
  }
}

// padded xb -> out[B,C,T] * mask
__global__ __launch_bounds__(256) void mask_out(const float* __restrict__ xp,
                                                const float* __restrict__ m,
                                                float* __restrict__ out) {
  int id = blockIdx.x * 256 + threadIdx.x;
  if (id < Bz * Cz * Tz) {
    int t = id & (Tz - 1), row = id >> 10, b = id >> 18;
    out[id] = xp[(size_t)row * TS + PADF + t] * m[b * Tz + t];
  }
}

// ---------------------------------------------------------------------------
// Fused QKV pointwise GEMM. Wave = 4 outputs x 256 t; weights via scalar path.
// grid (T/256=4, 192og/4=48, B=4), block 256 (4 independent waves).
// ---------------------------------------------------------------------------
__global__ __launch_bounds__(256) void qkv_gemm(
    const float* __restrict__ wq, const float* __restrict__ bq,
    const float* __restrict__ wk, const float* __restrict__ bk,
    const float* __restrict__ wv, const float* __restrict__ bv,
    const float* __restrict__ x, float* __restrict__ q, float* __restrict__ k,
    float* __restrict__ v) {
  const int lane = threadIdx.x & 63;
  const int wid = __builtin_amdgcn_readfirstlane(threadIdx.x >> 6);
  const int og = blockIdx.y * 4 + wid;  // 0..191
  const int o = og * 4;
  const int sect = o >> 8;  // 0:q 1:k 2:v (wave-uniform)
  const int oo = o & 255;
  const float* w = sect == 0 ? wq : (sect == 1 ? wk : wv);
  const float* bs = sect == 0 ? bq : (sect == 1 ? bk : bv);
  float* out = sect == 0 ? q : (sect == 1 ? k : v);
  const int t0 = blockIdx.x * 256, b = blockIdx.z;
  const int tL = t0 + lane * 4;
  const float* xrow = x + (size_t)b * Cz * TS + PADF + tL;
  float acc[4][4] = {};
#pragma unroll 4
  for (int c = 0; c < Cz; c++) {
    float4 xv = *(const float4*)(xrow + (size_t)c * TS);
#pragma unroll
    for (int oi = 0; oi < 4; oi++) {
      float ww = w[(size_t)(oo + oi) * Cz + c];  // wave-uniform -> s_load
      acc[oi][0] += ww * xv.x;
      acc[oi][1] += ww * xv.y;
      acc[oi][2] += ww * xv.z;
      acc[oi][3] += ww * xv.w;
    }
  }
#pragma unroll
  for (int oi = 0; oi < 4; oi++) {
    float bb = bs[oo + oi];
    *(float4*)&out[((size_t)b * Cz + oo + oi) * Tz + tL] = make_float4(
        acc[oi][0] + bb, acc[oi][1] + bb, acc[oi][2] + bb, acc[oi][3] + bb);
  }
}

// ---------------------------------------------------------------------------
// Output projection GEMM, c-split 2 for grid size. grid (4, 32, 4).
// Wave pair shares og; halves split Cin; LDS reduce at end.
// ---------------------------------------------------------------------------
__global__ __launch_bounds__(256) void wo_gemm(const float* __restrict__ w,
                                               const float* __restrict__ bias,
                                               const float* __restrict__ x,
                                               float* __restrict__ y) {
  __shared__ float red[2][4][260];
  const int lane = threadIdx.x & 63;
  const int wid = __builtin_amdgcn_readfirstlane(threadIdx.x >> 6);
  const int pair = wid >> 1, half = wid & 1;
  const int og = blockIdx.y * 2 + pair;  // 0..63
  const int o = og * 4;
  const int c0 = half * 128;
  const int t0 = blockIdx.x * 256, b = blockIdx.z;
  const int tL = lane * 4;
  const float* xrow = x + ((size_t)b * Cz + c0) * Tz + t0 + tL;
  float acc[4][4] = {};
#pragma unroll 4
  for (int c = 0; c < 128; c++) {
    float4 xv = *(const float4*)(xrow + (size_t)c * Tz);
#pragma unroll
    for (int oi = 0; oi < 4; oi++) {
      float ww = w[(size_t)(o + oi) * Cz + c0 + c];
      acc[oi][0] += ww * xv.x;
      acc[oi][1] += ww * xv.y;
      acc[oi][2] += ww * xv.z;
      acc[oi][3] += ww * xv.w;
    }
  }
  if (half == 1) {
#pragma unroll
    for (int oi = 0; oi < 4; oi++)
      *(float4*)&red[pair][oi][tL] =
          make_float4(acc[oi][0], acc[oi][1], acc[oi][2], acc[oi][3]);
  }
  __syncthreads();
  if (half == 0) {
#pragma unroll
    for (int oi = 0; oi < 4; oi++) {
      float4 r = *(float4*)&red[pair][oi][tL];
      float bb = bias[o + oi];
      *(float4*)&y[((size_t)b * Cz + o + oi) * Tz + t0 + tL] =
          make_float4(acc[oi][0] + r.x + bb, acc[oi][1] + r.y + bb,
                      acc[oi][2] + r.z + bb, acc[oi][3] + r.w + bb);
    }
  }
}

// ---------------------------------------------------------------------------
// K=3 conv as wave-independent implicit GEMM. Wave = 4 o x 256 t.
// CSPLIT=1: block's 4 waves = 4 o-groups (conv1). CSPLIT=4: 4 c-chunks + LDS
// reduce (conv2). IMASK: multiply input by mask taps (input unmasked).
// OPAD: output to padded layout. Output always *mask.
// grid (4, Cout/(CSPLIT==1?16:4), 4).
// ---------------------------------------------------------------------------
template <int CSPLIT, int RELU, int IMASK, int OPAD>
__global__ __launch_bounds__(256) void conv_w3(
    const float* __restrict__ w, const float* __restrict__ bias,
    const float* __restrict__ x, const float* __restrict__ mask,
    float* __restrict__ y, int Cout, int Cin) {
  const int lane = threadIdx.x & 63;
  const int wid = __builtin_amdgcn_readfirstlane(threadIdx.x >> 6);
  int og, c0, cN;
  if constexpr (CSPLIT == 1) {
    og = blockIdx.y * 4 + wid;
    c0 = 0;
    cN = Cin;
  } else {
    og = blockIdx.y;
    c0 = wid * (Cin / 4);
    cN = Cin / 4;
  }
  const int ob = og * 4;
  const int t0 = blockIdx.x * 256, b = blockIdx.z;
  const int tL = lane * 4;
  const float* mb = mask + (size_t)b * Tz;
  float mk[6];
  if constexpr (IMASK) {
#pragma unroll
    for (int j = 0; j < 6; j++) {
      int t = t0 + tL - 1 + j;
      mk[j] = (t >= 0 && t < Tz) ? mb[t] : 0.f;
    }
  }
  const float* xrow = x + ((size_t)b * Cin + c0) * TS + PADF + t0 + tL;
  float acc[4][4] = {};
  for (int cc = 0; cc < cN; cc += 2) {
    float xa[6], xc[6];
    {
      float4 m0 = *(const float4*)(xrow);
      float l0 = xrow[-1], r0 = xrow[4];
      const float* x2 = xrow + TS;
      float4 m1 = *(const float4*)(x2);
      float l1 = x2[-1], r1 = x2[4];
      xa[0] = l0; xa[1] = m0.x; xa[2] = m0.y; xa[3] = m0.z; xa[4] = m0.w; xa[5] = r0;
      xc[0] = l1; xc[1] = m1.x; xc[2] = m1.y; xc[3] = m1.z; xc[4] = m1.w; xc[5] = r1;
    }
    if constexpr (IMASK) {
#pragma unroll
      for (int j = 0; j < 6; j++) {
        xa[j] *= mk[j];
        xc[j] *= mk[j];
      }
    }
    const float* wp = w + ((size_t)ob * Cin + (c0 + cc)) * 3;  // uniform
#pragma unroll
    for (int oi = 0; oi < 4; oi++) {
      const float* wo_ = wp + (size_t)oi * Cin * 3;
      float w00 = wo_[0], w01 = wo_[1], w02 = wo_[2];
      float w10 = wo_[3], w11 = wo_[4], w12 = wo_[5];
#pragma unroll
      for (int j = 0; j < 4; j++)
        acc[oi][j] += w00 * xa[j] + w01 * xa[j + 1] + w02 * xa[j + 2] +
                      w10 * xc[j] + w11 * xc[j + 1] + w12 * xc[j + 2];
    }
    xrow += 2 * TS;
  }
  float4 mkv = *(const float4*)(mb + t0 + tL);
  if constexpr (CSPLIT == 1) {
#pragma unroll
    for (int oi = 0; oi < 4; oi++) {
      float bb = bias[ob + oi];
      float r[4];
#pragma unroll
      for (int j = 0; j < 4; j++) {
        float vv = acc[oi][j] + bb;
        if constexpr (RELU) vv = fmaxf(vv, 0.f);
        r[j] = vv * (&mkv.x)[j];
      }
      if constexpr (OPAD)
        *(float4*)&y[((size_t)b * Cout + ob + oi) * TS + PADF + t0 + tL] =
            make_float4(r[0], r[1], r[2], r[3]);
      else
        *(float4*)&y[((size_t)b * Cout + ob + oi) * Tz + t0 + tL] =
            make_float4(r[0], r[1], r[2], r[3]);
    }
  } else {
    __shared__ float red[4][4][260];
#pragma unroll
    for (int oi = 0; oi < 4; oi++)
      *(float4*)&red[wid][oi][tL] =
          make_float4(acc[oi][0], acc[oi][1], acc[oi][2], acc[oi][3]);
    __syncthreads();
    // wave `wid` finalizes output row ob+wid
    float4 s0 = *(float4*)&red[0][wid][tL];
    float4 s1 = *(float4*)&red[1][wid][tL];
    float4 s2 = *(float4*)&red[2][wid][tL];
    float4 s3 = *(float4*)&red[3][wid][tL];
    float bb = bias[ob + wid];
    float r[4];
    float sv[4] = {s0.x + s1.x + s2.x + s3.x, s0.y + s1.y + s2.y + s3.y,
                   s0.z + s1.z + s2.z + s3.z, s0.w + s1.w + s2.w + s3.w};
#pragma unroll
    for (int j = 0; j < 4; j++) {
      float vv = sv[j] + bb;
      if constexpr (RELU) vv = fmaxf(vv, 0.f);
      r[j] = vv * (&mkv.x)[j];
    }
    if constexpr (OPAD)
      *(float4*)&y[((size_t)b * Cout + ob + wid) * TS + PADF + t0 + tL] =
          make_float4(r[0], r[1], r[2], r[3]);
    else
      *(float4*)&y[((size_t)b * Cout + ob + wid) * Tz + t0 + tL] =
          make_float4(r[0], r[1], r[2], r[3]);
  }
}

// ---------------------------------------------------------------------------
// Flash-style attention with banded relative-position terms (unchanged).
// q,k,v,ao plain [B,C,T]. grid (T/64, B*H), block (16,16).
// ---------------------------------------------------------------------------
__global__ __launch_bounds__(256) void attn_kernel(
    const float* __restrict__ q, const float* __restrict__ k,
    const float* __restrict__ v, const float* __restrict__ mask,
    const float* __restrict__ erk, const float* __restrict__ erv,
    float* __restrict__ y) {
  __shared__ float Qs[64][64];
  __shared__ float SK[64][65];
  __shared__ float Vs[64][65];
  __shared__ float band[64][NR];
  __shared__ float rq[64][NR];
  __shared__ float mrow[64], lrow[64], arow[64];

  const int tx = threadIdx.x, ty = threadIdx.y;
  const int tid = ty * 16 + tx;
  const int i0 = blockIdx.x * 64;
  const int b = blockIdx.y >> 2, h = blockIdx.y & 3;
  const float* qb = q + ((size_t)b * Cz + h * KCz) * Tz;
  const float* kb = k + ((size_t)b * Cz + h * KCz) * Tz;
  const float* vb = v + ((size_t)b * Cz + h * KCz) * Tz;
  const float* mb = mask + (size_t)b * Tz;

  for (int id = tid; id < 64 * 64; id += 256) {
    int i = id & 63, d = id >> 6;
    Qs[d][i] = qb[(size_t)d * Tz + i0 + i] * 0.125f;
  }
  if (tid < 64) {
    mrow[tid] = -1e30f;
    lrow[tid] = 0.f;
  }
  for (int id = tid; id < 64 * NR; id += 256) band[id / NR][id % NR] = -1e30f;
  __syncthreads();
  for (int id = tid; id < 64 * NR; id += 256) {
    int i = id / NR, r = id % NR;
    float s = 0.f;
    for (int d = 0; d < KCz; d++) s += Qs[d][i] * erk[r * KCz + d];
    rq[i][r] = s;
  }

  float qmk[4];
#pragma unroll
  for (int ii = 0; ii < 4; ii++) qmk[ii] = mb[i0 + ty + 16 * ii];

  float acc[4][4] = {};

  for (int j0 = 0; j0 < Tz; j0 += 64) {
    __syncthreads();
    for (int id = tid; id < 64 * 64; id += 256) {
      int j = id & 63, d = id >> 6;
      SK[d][j] = kb[(size_t)d * Tz + j0 + j];
      Vs[d][j] = vb[(size_t)d * Tz + j0 + j];
    }
    float kmk[4];
#pragma unroll
    for (int jj = 0; jj < 4; jj++) kmk[jj] = mb[j0 + tx * 4 + jj];
    __syncthreads();

    float sc[4][4] = {};
#pragma unroll 4
    for (int d = 0; d < 64; d++) {
      float a[4], bv[4];
#pragma unroll
      for (int ii = 0; ii < 4; ii++) a[ii] = Qs[d][ty + 16 * ii];
#pragma unroll
      for (int jj = 0; jj < 4; jj++) bv[jj] = SK[d][tx * 4 + jj];
#pragma unroll
      for (int ii = 0; ii < 4; ii++)
#pragma unroll
        for (int jj = 0; jj < 4; jj++) sc[ii][jj] += a[ii] * bv[jj];
    }
    float mx[4];
#pragma unroll
    for (int ii = 0; ii < 4; ii++) {
      int i = ty + 16 * ii, ig = i0 + i;
      float m = -1e30f;
#pragma unroll
      for (int jj = 0; jj < 4; jj++) {
        int j = tx * 4 + jj, jg = j0 + j;
        float s = sc[ii][jj];
        int dl = jg - ig;
        if (dl >= -Wz && dl <= Wz) s += rq[i][dl + Wz];
        if (qmk[ii] * kmk[jj] == 0.f) s = -1e4f;
        sc[ii][jj] = s;
        if (dl >= -Wz && dl <= Wz) band[i][dl + Wz] = s;
        m = fmaxf(m, s);
      }
      mx[ii] = m;
    }
#pragma unroll
    for (int off = 1; off < 16; off <<= 1) {
#pragma unroll
      for (int ii = 0; ii < 4; ii++)
        mx[ii] = fmaxf(mx[ii], __shfl_xor(mx[ii], off, 16));
    }
    if (tx == 0) {
#pragma unroll
      for (int ii = 0; ii < 4; ii++) {
        int i = ty + 16 * ii;
        float nm = fmaxf(mrow[i], mx[ii]);
        float al = __expf(mrow[i] - nm);
        mrow[i] = nm;
        arow[i] = al;
        lrow[i] *= al;
      }
    }
    __syncthreads();

    float sm[4];
#pragma unroll
    for (int ii = 0; ii < 4; ii++) {
      int i = ty + 16 * ii;
      float m = mrow[i], s = 0.f;
#pragma unroll
      for (int jj = 0; jj < 4; jj++) {
        float p = __expf(sc[ii][jj] - m);
        SK[i][tx * 4 + jj] = p;
        s += p;
      }
      sm[ii] = s;
    }
#pragma unroll
    for (int off = 1; off < 16; off <<= 1) {
#pragma unroll
      for (int ii = 0; ii < 4; ii++) sm[ii] += __shfl_xor(sm[ii], off, 16);
    }
    if (tx == 0) {
#pragma unroll
      for (int ii = 0; ii < 4; ii++) lrow[ty + 16 * ii] += sm[ii];
    }
#pragma unroll
    for (int ii = 0; ii < 4; ii++) {
      float al = arow[ty + 16 * ii];
#pragma unroll
      for (int jj = 0; jj < 4; jj++) acc[ii][jj] *= al;
    }
    __syncthreads();

#pragma unroll 4
    for (int j = 0; j < 64; j++) {
      float p[4], vv[4];
#pragma unroll
      for (int ii = 0; ii < 4; ii++) p[ii] = SK[ty + 16 * ii][j];
#pragma unroll
      for (int jj = 0; jj < 4; jj++) vv[jj] = Vs[tx * 4 + jj][j];
#pragma unroll
      for (int ii = 0; ii < 4; ii++)
#pragma unroll
        for (int jj = 0; jj < 4; jj++) acc[ii][jj] += p[ii] * vv[jj];
    }
  }

  __syncthreads();
  float* ervs = &rq[0][0];
  for (int id = tid; id < NR * KCz; id += 256) ervs[id] = erv[id];
  for (int id = tid; id < 64 * NR; id += 256) {
    int i = id / NR, r = id % NR;
    band[i][r] = __expf(band[i][r] - mrow[i]);
  }
  __syncthreads();
#pragma unroll
  for (int ii = 0; ii < 4; ii++) {
    int i = ty + 16 * ii;
    float li = 1.f / lrow[i];
    float o[4];
#pragma unroll
    for (int jj = 0; jj < 4; jj++) o[jj] = acc[ii][jj];
    for (int r = 0; r < NR; r++) {
      float pb = band[i][r];
#pragma unroll
      for (int jj = 0; jj < 4; jj++) o[jj] += pb * ervs[r * KCz + tx * 4 + jj];
    }
#pragma unroll
    for (int jj = 0; jj < 4; jj++) acc[ii][jj] = o[jj] * li;
  }
  __syncthreads();
#pragma unroll
  for (int ii = 0; ii < 4; ii++)
#pragma unroll
    for (int jj = 0; jj < 4; jj++) SK[tx * 4 + jj][ty + 16 * ii] = acc[ii][jj];
  __syncthreads();
  for (int id = tid; id < 64 * 64; id += 256) {
    int i = id & 63, d = id >> 6;
    y[((size_t)b * Cz + h * KCz + d) * Tz + i0 + i] = SK[d][i];
  }
}

// ---------------------------------------------------------------------------
// In-place residual + channel LayerNorm: x(padded) = LN(x + y)*g + b
// grid (T/64, B), block 256.
// ---------------------------------------------------------------------------
__global__ __launch_bounds__(256) void add_ln(float* __restrict__ x,
                                              const float* __restrict__ y,
                                              const float* __restrict__ g,
                                              const float* __restrict__ bb) {
  __shared__ float red[8][64];
  __shared__ float ms[64], rs[64];
  const int tid = threadIdx.x;
  const int t0 = blockIdx.x * 64, b = blockIdx.y;
  const int tl = tid & 63, grp = tid >> 6;
  const size_t bx = (size_t)b * Cz * TS + PADF + t0 + tl;
  const size_t by = (size_t)b * Cz * Tz + t0 + tl;
  float s = 0.f, sq = 0.f;
  for (int c = grp; c < Cz; c += 4) {
    float v = x[bx + (size_t)c * TS] + y[by + (size_t)c * Tz];
    s += v;
    sq += v * v;
  }
  red[grp][tl] = s;
  red[4 + grp][tl] = sq;
  __syncthreads();
  if (tid < 64) {
    float su = red[0][tid] + red[1][tid] + red[2][tid] + red[3][tid];
    float sqq = red[4][tid] + red[5][tid] + red[6][tid] + red[7][tid];
    float m = su * (1.f / Cz);
    float var = sqq * (1.f / Cz) - m * m;
    ms[tid] = m;
    rs[tid] = rsqrtf(var + 1e-5f);
  }
  __syncthreads();
  float m = ms[tl], r = rs[tl];
  for (int c = grp; c < Cz; c += 4) {
    float v = x[bx + (size_t)c * TS] + y[by + (size_t)c * Tz];
    x[bx + (size_t)c * TS] = (v - m) * r * g[c] + bb[c];
  }
}

// ---------------------------------------------------------------------------
extern "C" void kernel_launch(void* const* d_in, const int* in_sizes, int n_in,
                              void* d_out, int out_size, void* d_ws,
                              size_t ws_size, hipStream_t stream) {
  const float* x = (const float*)d_in[0];
  const float* xm = (const float*)d_in[1];
  const float* wq = (const float*)d_in[2];
  const float* bq = (const float*)d_in[3];
  const float* wk = (const float*)d_in[4];
  const float* bk = (const float*)d_in[5];
  const float* wv = (const float*)d_in[6];
  const float* bv = (const float*)d_in[7];
  const float* wo = (const float*)d_in[8];
  const float* bo = (const float*)d_in[9];
  const float* erk = (const float*)d_in[10];
  const float* erv = (const float*)d_in[11];
  const float* g1 = (const float*)d_in[12];
  const float* b1 = (const float*)d_in[13];
  const float* fw1 = (const float*)d_in[14];
  const float* fb1 = (const float*)d_in[15];
  const float* fw2 = (const float*)d_in[16];
  const float* fb2 = (const float*)d_in[17];
  const float* g2 = (const float*)d_in[18];
  const float* b2 = (const float*)d_in[19];

  const size_t XBN = (size_t)Bz * Cz * TS;   // padded activation
  const size_t NBC = (size_t)Bz * Cz * Tz;   // plain activation
  float* ws = (float*)d_ws;
  float* xb = ws;             // padded [B,C,TS]
  float* yb = ws + XBN;       // plain  [B,C,T]
  float* qb = yb + NBC;       // plain; region also hosts h (padded [B,FC,TS])
  float* kb = qb + NBC;
  float* vb2 = kb + NBC;
  float* ao = vb2 + NBC;
  float* hb = qb;  // aliases q/k/v/ao (dead by conv1 time)

  const int ntot = (int)NBC;
  zero_pads<<<dim3((Bz * Cz * 8 + 255) / 256), 256, 0, stream>>>(xb, Bz * Cz);
  mask_in<<<dim3((ntot + 255) / 256), 256, 0, stream>>>(x, xm, xb);
  for (int l = 0; l < Lz; l++) {
    qkv_gemm<<<dim3(4, 48, 4), 256, 0, stream>>>(
        wq + (size_t)l * Cz * Cz, bq + l * Cz, wk + (size_t)l * Cz * Cz,
        bk + l * Cz, wv + (size_t)l * Cz * Cz, bv + l * Cz, xb, qb, kb, vb2);
    attn_kernel<<<dim3(16, 16), dim3(16, 16), 0, stream>>>(
        qb, kb, vb2, xm, erk + l * NR * KCz, erv + l * NR * KCz, ao);
    wo_gemm<<<dim3(4, 32, 4), 256, 0, stream>>>(wo + (size_t)l * Cz * Cz,
                                                bo + l * Cz, ao, yb);
    add_ln<<<dim3(16, 4), 256, 0, stream>>>(xb, yb, g1 + l * Cz, b1 + l * Cz);
    zero_pads<<<dim3((Bz * FCz * 8 + 255) / 256), 256, 0, stream>>>(hb,
                                                                    Bz * FCz);
    conv_w3<1, 1, 1, 1><<<dim3(4, 64, 4), 256, 0, stream>>>(
        fw1 + (size_t)l * FCz * Cz * 3, fb1 + l * FCz, xb, xm, hb, FCz, Cz);
    conv_w3<4, 0, 0, 0><<<dim3(4, 64, 4), 256, 0, stream>>>(
        fw2 + (size_t)l * Cz * FCz * 3, fb2 + l * Cz, hb, xm, yb, Cz, FCz);
    add_ln<<<dim3(16, 4), 256, 0, stream>>>(xb, yb, g2 + l * Cz, b2 + l * Cz);
  }
  mask_out<<<dim3((ntot + 255) / 256), 256, 0, stream>>>(xb, xm,
                                                         (float*)d_out);
}

// Round 4
// 2455.350 us; speedup vs baseline: 2.2775x; 1.1668x over previous
//
#include <hip/hip_runtime.h>

// Encoder: L=6 layers of (rel-pos attention + channel-LN + K=3 conv FFN + LN)
// B=4, C=256, T=1024, H=4, KC=64, FC=1024, W=10, fp32 I/O.
// GEMMs/convs: split-bf16 (hi/lo) emulated-fp32 MFMA (3 passes of
// mfma_f32_16x16x32_bf16). Attention: fp32 flash-style (unchanged).

#define Lz 6
#define Cz 256
#define FCz 1024
#define Hz 4
#define Wz 10
#define Bz 4
#define Tz 1024
#define KCz 64
#define NR 21
#define TS 1032  // padded fp32 activation row stride
#define PADF 4
#define PROWS 1026  // packed channel-last rows: 1 halo + 1024 + 1 halo

typedef unsigned short u16;
typedef __attribute__((ext_vector_type(8))) short bf8v;   // 8 bf16 = 4 VGPR
typedef __attribute__((ext_vector_type(4))) float f4v;

__device__ inline void bf_split(float v, u16& hi, u16& lo) {
  unsigned u = __float_as_uint(v);
  unsigned hr = (u + 0x7FFFu + ((u >> 16) & 1u)) >> 16;
  float rem = v - __uint_as_float(hr << 16);
  unsigned u2 = __float_as_uint(rem);
  unsigned lr = (u2 + 0x7FFFu + ((u2 >> 16) & 1u)) >> 16;
  hi = (u16)hr;
  lo = (u16)lr;
}

// ---------------------------------------------------------------------------
__global__ __launch_bounds__(256) void mask_in(const float* __restrict__ x,
                                               const float* __restrict__ m,
                                               float* __restrict__ xp) {
  int id = blockIdx.x * 256 + threadIdx.x;
  if (id < Bz * Cz * Tz) {
    int t = id & (Tz - 1), row = id >> 10, b = id >> 18;
    xp[(size_t)row * TS + PADF + t] = x[id] * m[b * Tz + t];
  }
}

__global__ __launch_bounds__(256) void mask_out(const float* __restrict__ xp,
                                                const float* __restrict__ m,
                                                float* __restrict__ out) {
  int id = blockIdx.x * 256 + threadIdx.x;
  if (id < Bz * Cz * Tz) {
    int t = id & (Tz - 1), row = id >> 10, b = id >> 18;
    out[id] = xp[(size_t)row * TS + PADF + t] * m[b * Tz + t];
  }
}

// zero halo rows (0 and 1025) of packed [B][1026][Cd] hi/lo pair
__global__ __launch_bounds__(256) void zero_halo(u16* hi, u16* lo, int Cd) {
  int id = blockIdx.x * 256 + threadIdx.x;
  if (id >= Bz * 2 * Cd) return;
  int c = id % Cd, rb = id / Cd, b = rb >> 1, s = rb & 1;
  size_t a = ((size_t)b * PROWS + (s ? (PROWS - 1) : 0)) * Cd + c;
  hi[a] = 0;
  lo[a] = 0;
}

// ---------------------------------------------------------------------------
// Transpose-pack: fp32 [b][Cd][sstride(+soff)] -> bf16 hi/lo [b][1026][Cd],
// data rows at +1, optional mask multiply. grid (T/64, Cd/64, B), block 256.
// ---------------------------------------------------------------------------
__global__ __launch_bounds__(256) void tpack(const float* __restrict__ src,
                                             int sstride, int soff,
                                             const float* __restrict__ mask,
                                             int amask, u16* __restrict__ dhi,
                                             u16* __restrict__ dlo, int Cd) {
  __shared__ float L[64 * 68];
  const int tid = threadIdx.x;
  const int t0 = blockIdx.x * 64, c0 = blockIdx.y * 64, b = blockIdx.z;
  const float* sb = src + (size_t)b * Cd * sstride + soff;
#pragma unroll
  for (int i = 0; i < 16; i++) {
    int id = tid + 256 * i;
    int cc = id >> 6, tt = id & 63;
    L[cc * 68 + tt] = sb[(size_t)(c0 + cc) * sstride + t0 + tt];
  }
  __syncthreads();
  const int tt = tid >> 2, p = tid & 3;
  float mv = amask ? mask[(size_t)b * Tz + t0 + tt] : 1.f;
  u16 hs[16], ls[16];
#pragma unroll
  for (int j = 0; j < 16; j++) {
    float v = L[(p * 16 + j) * 68 + tt] * mv;
    bf_split(v, hs[j], ls[j]);
  }
  size_t da = ((size_t)b * PROWS + t0 + tt + 1) * Cd + c0 + p * 16;
  *(uint4*)&dhi[da] = *(uint4*)&hs[0];
  *(uint4*)&dhi[da + 8] = *(uint4*)&hs[8];
  *(uint4*)&dlo[da] = *(uint4*)&ls[0];
  *(uint4*)&dlo[da + 8] = *(uint4*)&ls[8];
}

// ---------------------------------------------------------------------------
// Pack q,k,v,o weights into A[1024][256] hi/lo + concatenated bias[1024].
// ---------------------------------------------------------------------------
__global__ __launch_bounds__(256) void pack_qkvwo(
    const float* __restrict__ wq, const float* __restrict__ wk,
    const float* __restrict__ wv, const float* __restrict__ wo_,
    const float* __restrict__ bq, const float* __restrict__ bk,
    const float* __restrict__ bv, const float* __restrict__ bo,
    u16* __restrict__ hi, u16* __restrict__ lo, float* __restrict__ pb) {
  int id = blockIdx.x * 256 + threadIdx.x;
  if (id >= 1024 * 256) return;
  int o = id >> 8, c = id & 255;
  int sel = o >> 8;
  const float* w = sel == 0 ? wq : (sel == 1 ? wk : (sel == 2 ? wv : wo_));
  float v = w[((size_t)(o & 255) << 8) + c];
  bf_split(v, hi[id], lo[id]);
  if (id < 1024) {
    int s2 = id >> 8;
    const float* bs = s2 == 0 ? bq : (s2 == 1 ? bk : (s2 == 2 ? bv : bo));
    pb[id] = bs[id & 255];
  }
}

// Pack conv weights fw[Cout][Cin][3] -> A[tap][Cout][Cin] hi/lo.
__global__ __launch_bounds__(256) void pack_w3(const float* __restrict__ fw,
                                               u16* __restrict__ hi,
                                               u16* __restrict__ lo, int Cout,
                                               int Cin) {
  int id = blockIdx.x * 256 + threadIdx.x;
  if (id >= 3 * Cout * Cin) return;
  int c = id % Cin, rest = id / Cin;
  int o = rest % Cout, tap = rest / Cout;
  float v = fw[((size_t)o * Cin + c) * 3 + tap];
  bf_split(v, hi[id], lo[id]);
}

// ---------------------------------------------------------------------------
// Split-bf16 MFMA GEMM: D[m][t] = sum_{tap,c} A[tap][m][c] * Bp[t+tap][c]
// A: hi/lo [TAPS][M][Kc]; Bp: hi/lo packed [B][1026][Kc] (data rows +1).
// Block tile 64m x 64t, 4 waves of 32x32, K-tile 32; 3 mfma passes per tile
// (AhBh + AlBh + AhBl). grid (Tz/64, Mtiles, B).
// EPI 0: route to q/k/v fp32 [b][256][Tz] by (m>>8).
// EPI 1: out fp32 [b][256][Tz] rows (m - out_moff), optional mask.
// EPI 2: relu + mask, split -> packed hi/lo [B][1026][M] rows +1 (conv1).
// ---------------------------------------------------------------------------
template <int TAPS, int EPI>
__global__ __launch_bounds__(256) void mfma_gemm(
    const u16* __restrict__ Ah, const u16* __restrict__ Al,
    const u16* __restrict__ Bh, const u16* __restrict__ Bl,
    const float* __restrict__ bias, const float* __restrict__ mask,
    float* __restrict__ oq, float* __restrict__ ok, float* __restrict__ ov,
    float* __restrict__ out, int out_moff, int amask, u16* __restrict__ ph,
    u16* __restrict__ pl, int M, int Kc, int m_base) {
  __shared__ u16 sm[4 * 64 * 40];  // Ash, Asl, Bsh, Bsl (K-tile rows pad 40)
  u16* Ash = sm;
  u16* Asl = sm + 2560;
  u16* Bsh = sm + 5120;
  u16* Bsl = sm + 7680;
  const int tid = threadIdx.x;
  const int lane = tid & 63, wid = tid >> 6;
  const int wm = wid & 1, wn = wid >> 1;
  const int r = lane & 15, qd = lane >> 4;
  const int t0 = blockIdx.x * 64;
  const int m0 = blockIdx.y * 64 + m_base;
  const int b = blockIdx.z;
  const int srow = tid >> 2, sseg = (tid & 3) * 8;

  f4v acc[2][2];
#pragma unroll
  for (int i = 0; i < 2; i++)
#pragma unroll
    for (int j = 0; j < 2; j++) acc[i][j] = (f4v)(0.f);

  for (int tap = 0; tap < TAPS; tap++) {
    const u16* Ath = Ah + (size_t)tap * M * Kc;
    const u16* Atl = Al + (size_t)tap * M * Kc;
    const int tofs = (TAPS == 1) ? 1 : tap;
    const size_t arow = (size_t)(m0 + srow) * Kc;
    const size_t brow = ((size_t)b * PROWS + t0 + tofs + srow) * Kc;
    for (int kc = 0; kc < Kc; kc += 32) {
      *(uint4*)&Ash[srow * 40 + sseg] = *(const uint4*)&Ath[arow + kc + sseg];
      *(uint4*)&Asl[srow * 40 + sseg] = *(const uint4*)&Atl[arow + kc + sseg];
      *(uint4*)&Bsh[srow * 40 + sseg] = *(const uint4*)&Bh[brow + kc + sseg];
      *(uint4*)&Bsl[srow * 40 + sseg] = *(const uint4*)&Bl[brow + kc + sseg];
      __syncthreads();
      bf8v ah[2], al[2], bh[2], bl[2];
#pragma unroll
      for (int f = 0; f < 2; f++) {
        int ar = (wm * 32 + f * 16 + r) * 40 + qd * 8;
        int br = (wn * 32 + f * 16 + r) * 40 + qd * 8;
        ah[f] = *(bf8v*)&Ash[ar];
        al[f] = *(bf8v*)&Asl[ar];
        bh[f] = *(bf8v*)&Bsh[br];
        bl[f] = *(bf8v*)&Bsl[br];
      }
#pragma unroll
      for (int mf = 0; mf < 2; mf++)
#pragma unroll
        for (int nf = 0; nf < 2; nf++) {
          acc[mf][nf] = __builtin_amdgcn_mfma_f32_16x16x32_bf16(
              ah[mf], bh[nf], acc[mf][nf], 0, 0, 0);
          acc[mf][nf] = __builtin_amdgcn_mfma_f32_16x16x32_bf16(
              al[mf], bh[nf], acc[mf][nf], 0, 0, 0);
          acc[mf][nf] = __builtin_amdgcn_mfma_f32_16x16x32_bf16(
              ah[mf], bl[nf], acc[mf][nf], 0, 0, 0);
        }
      __syncthreads();
    }
  }

  float* Ds = (float*)sm;  // 64x68 fp32 staging (17.4 KB <= 20.5 KB)
  if constexpr (EPI == 2) {
    // Ds[n][m]
#pragma unroll
    for (int mf = 0; mf < 2; mf++)
#pragma unroll
      for (int nf = 0; nf < 2; nf++) {
        int nl = wn * 32 + nf * 16 + r;
        int ml = wm * 32 + mf * 16 + qd * 4;
        *(f4v*)&Ds[nl * 68 + ml] = acc[mf][nf];
      }
    __syncthreads();
    const int row = tid >> 2, p = tid & 3;
    const int t = t0 + row;
    float mv = mask[(size_t)b * Tz + t];
    u16 hs[16], ls[16];
#pragma unroll
    for (int jj = 0; jj < 4; jj++) {
      float4 dv = *(float4*)&Ds[row * 68 + p * 16 + jj * 4];
      float4 bb = *(const float4*)&bias[m0 + p * 16 + jj * 4];
      float vv[4] = {dv.x + bb.x, dv.y + bb.y, dv.z + bb.z, dv.w + bb.w};
#pragma unroll
      for (int e = 0; e < 4; e++) {
        float v = fmaxf(vv[e], 0.f) * mv;
        bf_split(v, hs[jj * 4 + e], ls[jj * 4 + e]);
      }
    }
    size_t da = ((size_t)b * PROWS + t + 1) * M + m0 + p * 16;
    *(uint4*)&ph[da] = *(uint4*)&hs[0];
    *(uint4*)&ph[da + 8] = *(uint4*)&hs[8];
    *(uint4*)&pl[da] = *(uint4*)&ls[0];
    *(uint4*)&pl[da + 8] = *(uint4*)&ls[8];
  } else {
    // Ds[m][n]
#pragma unroll
    for (int mf = 0; mf < 2; mf++)
#pragma unroll
      for (int nf = 0; nf < 2; nf++) {
        int ml = wm * 32 + mf * 16 + qd * 4;
        int nl = wn * 32 + nf * 16 + r;
#pragma unroll
        for (int e = 0; e < 4; e++) Ds[(ml + e) * 68 + nl] = acc[mf][nf][e];
      }
    __syncthreads();
    const int row = tid >> 2, p = tid & 3;
    const int m = m0 + row;
    const float bb = bias[m];
    if constexpr (EPI == 0) {
      int sel = m >> 8;
      float* op = sel == 0 ? oq : (sel == 1 ? ok : ov);
      size_t oa = ((size_t)b * Cz + (m & 255)) * Tz + t0 + p * 16;
#pragma unroll
      for (int jj = 0; jj < 4; jj++) {
        float4 dv = *(float4*)&Ds[row * 68 + p * 16 + jj * 4];
        *(float4*)&op[oa + jj * 4] =
            make_float4(dv.x + bb, dv.y + bb, dv.z + bb, dv.w + bb);
      }
    } else {
      size_t oa = ((size_t)b * Cz + (m - out_moff)) * Tz + t0 + p * 16;
#pragma unroll
      for (int jj = 0; jj < 4; jj++) {
        float4 dv = *(float4*)&Ds[row * 68 + p * 16 + jj * 4];
        float4 rv = make_float4(dv.x + bb, dv.y + bb, dv.z + bb, dv.w + bb);
        if (amask) {
          float4 mk = *(const float4*)&mask[(size_t)b * Tz + t0 + p * 16 + jj * 4];
          rv.x *= mk.x; rv.y *= mk.y; rv.z *= mk.z; rv.w *= mk.w;
        }
        *(float4*)&out[oa + jj * 4] = rv;
      }
    }
  }
}

// ---------------------------------------------------------------------------
// Flash-style attention with banded relative-position terms (fp32).
// q,k,v,y plain [B,C,T]. grid (T/64, B*H), block (16,16).
// ---------------------------------------------------------------------------
__global__ __launch_bounds__(256) void attn_kernel(
    const float* __restrict__ q, const float* __restrict__ k,
    const float* __restrict__ v, const float* __restrict__ mask,
    const float* __restrict__ erk, const float* __restrict__ erv,
    float* __restrict__ y) {
  __shared__ float Qs[64][64];
  __shared__ float SK[64][65];
  __shared__ float Vs[64][65];
  __shared__ float band[64][NR];
  __shared__ float rq[64][NR];
  __shared__ float mrow[64], lrow[64], arow[64];

  const int tx = threadIdx.x, ty = threadIdx.y;
  const int tid = ty * 16 + tx;
  const int i0 = blockIdx.x * 64;
  const int b = blockIdx.y >> 2, h = blockIdx.y & 3;
  const float* qb = q + ((size_t)b * Cz + h * KCz) * Tz;
  const float* kb = k + ((size_t)b * Cz + h * KCz) * Tz;
  const float* vb = v + ((size_t)b * Cz + h * KCz) * Tz;
  const float* mb = mask + (size_t)b * Tz;

  for (int id = tid; id < 64 * 64; id += 256) {
    int i = id & 63, d = id >> 6;
    Qs[d][i] = qb[(size_t)d * Tz + i0 + i] * 0.125f;
  }
  if (tid < 64) {
    mrow[tid] = -1e30f;
    lrow[tid] = 0.f;
  }
  for (int id = tid; id < 64 * NR; id += 256) band[id / NR][id % NR] = -1e30f;
  __syncthreads();
  for (int id = tid; id < 64 * NR; id += 256) {
    int i = id / NR, r = id % NR;
    float s = 0.f;
    for (int d = 0; d < KCz; d++) s += Qs[d][i] * erk[r * KCz + d];
    rq[i][r] = s;
  }

  float qmk[4];
#pragma unroll
  for (int ii = 0; ii < 4; ii++) qmk[ii] = mb[i0 + ty + 16 * ii];

  float acc[4][4] = {};

  for (int j0 = 0; j0 < Tz; j0 += 64) {
    __syncthreads();
    for (int id = tid; id < 64 * 64; id += 256) {
      int j = id & 63, d = id >> 6;
      SK[d][j] = kb[(size_t)d * Tz + j0 + j];
      Vs[d][j] = vb[(size_t)d * Tz + j0 + j];
    }
    float kmk[4];
#pragma unroll
    for (int jj = 0; jj < 4; jj++) kmk[jj] = mb[j0 + tx * 4 + jj];
    __syncthreads();

    float sc[4][4] = {};
#pragma unroll 4
    for (int d = 0; d < 64; d++) {
      float a[4], bv[4];
#pragma unroll
      for (int ii = 0; ii < 4; ii++) a[ii] = Qs[d][ty + 16 * ii];
#pragma unroll
      for (int jj = 0; jj < 4; jj++) bv[jj] = SK[d][tx * 4 + jj];
#pragma unroll
      for (int ii = 0; ii < 4; ii++)
#pragma unroll
        for (int jj = 0; jj < 4; jj++) sc[ii][jj] += a[ii] * bv[jj];
    }
    float mx[4];
#pragma unroll
    for (int ii = 0; ii < 4; ii++) {
      int i = ty + 16 * ii, ig = i0 + i;
      float m = -1e30f;
#pragma unroll
      for (int jj = 0; jj < 4; jj++) {
        int j = tx * 4 + jj, jg = j0 + j;
        float s = sc[ii][jj];
        int dl = jg - ig;
        if (dl >= -Wz && dl <= Wz) s += rq[i][dl + Wz];
        if (qmk[ii] * kmk[jj] == 0.f) s = -1e4f;
        sc[ii][jj] = s;
        if (dl >= -Wz && dl <= Wz) band[i][dl + Wz] = s;
        m = fmaxf(m, s);
      }
      mx[ii] = m;
    }
#pragma unroll
    for (int off = 1; off < 16; off <<= 1) {
#pragma unroll
      for (int ii = 0; ii < 4; ii++)
        mx[ii] = fmaxf(mx[ii], __shfl_xor(mx[ii], off, 16));
    }
    if (tx == 0) {
#pragma unroll
      for (int ii = 0; ii < 4; ii++) {
        int i = ty + 16 * ii;
        float nm = fmaxf(mrow[i], mx[ii]);
        float al = __expf(mrow[i] - nm);
        mrow[i] = nm;
        arow[i] = al;
        lrow[i] *= al;
      }
    }
    __syncthreads();

    float sm[4];
#pragma unroll
    for (int ii = 0; ii < 4; ii++) {
      int i = ty + 16 * ii;
      float m = mrow[i], s = 0.f;
#pragma unroll
      for (int jj = 0; jj < 4; jj++) {
        float p = __expf(sc[ii][jj] - m);
        SK[i][tx * 4 + jj] = p;
        s += p;
      }
      sm[ii] = s;
    }
#pragma unroll
    for (int off = 1; off < 16; off <<= 1) {
#pragma unroll
      for (int ii = 0; ii < 4; ii++) sm[ii] += __shfl_xor(sm[ii], off, 16);
    }
    if (tx == 0) {
#pragma unroll
      for (int ii = 0; ii < 4; ii++) lrow[ty + 16 * ii] += sm[ii];
    }
#pragma unroll
    for (int ii = 0; ii < 4; ii++) {
      float al = arow[ty + 16 * ii];
#pragma unroll
      for (int jj = 0; jj < 4; jj++) acc[ii][jj] *= al;
    }
    __syncthreads();

#pragma unroll 4
    for (int j = 0; j < 64; j++) {
      float p[4], vv[4];
#pragma unroll
      for (int ii = 0; ii < 4; ii++) p[ii] = SK[ty + 16 * ii][j];
#pragma unroll
      for (int jj = 0; jj < 4; jj++) vv[jj] = Vs[tx * 4 + jj][j];
#pragma unroll
      for (int ii = 0; ii < 4; ii++)
#pragma unroll
        for (int jj = 0; jj < 4; jj++) acc[ii][jj] += p[ii] * vv[jj];
    }
  }

  __syncthreads();
  float* ervs = &rq[0][0];
  for (int id = tid; id < NR * KCz; id += 256) ervs[id] = erv[id];
  for (int id = tid; id < 64 * NR; id += 256) {
    int i = id / NR, r = id % NR;
    band[i][r] = __expf(band[i][r] - mrow[i]);
  }
  __syncthreads();
#pragma unroll
  for (int ii = 0; ii < 4; ii++) {
    int i = ty + 16 * ii;
    float li = 1.f / lrow[i];
    float o[4];
#pragma unroll
    for (int jj = 0; jj < 4; jj++) o[jj] = acc[ii][jj];
    for (int r = 0; r < NR; r++) {
      float pb = band[i][r];
#pragma unroll
      for (int jj = 0; jj < 4; jj++) o[jj] += pb * ervs[r * KCz + tx * 4 + jj];
    }
#pragma unroll
    for (int jj = 0; jj < 4; jj++) acc[ii][jj] = o[jj] * li;
  }
  __syncthreads();
#pragma unroll
  for (int ii = 0; ii < 4; ii++)
#pragma unroll
    for (int jj = 0; jj < 4; jj++) SK[tx * 4 + jj][ty + 16 * ii] = acc[ii][jj];
  __syncthreads();
  for (int id = tid; id < 64 * 64; id += 256) {
    int i = id & 63, d = id >> 6;
    y[((size_t)b * Cz + h * KCz + d) * Tz + i0 + i] = SK[d][i];
  }
}

// ---------------------------------------------------------------------------
// In-place residual + channel LayerNorm: x(padded) = LN(x + y)*g + b
// ---------------------------------------------------------------------------
__global__ __launch_bounds__(256) void add_ln(float* __restrict__ x,
                                              const float* __restrict__ y,
                                              const float* __restrict__ g,
                                              const float* __restrict__ bb) {
  __shared__ float red[8][64];
  __shared__ float ms[64], rs[64];
  const int tid = threadIdx.x;
  const int t0 = blockIdx.x * 64, b = blockIdx.y;
  const int tl = tid & 63, grp = tid >> 6;
  const size_t bx = (size_t)b * Cz * TS + PADF + t0 + tl;
  const size_t by = (size_t)b * Cz * Tz + t0 + tl;
  float s = 0.f, sq = 0.f;
  for (int c = grp; c < Cz; c += 4) {
    float v = x[bx + (size_t)c * TS] + y[by + (size_t)c * Tz];
    s += v;
    sq += v * v;
  }
  red[grp][tl] = s;
  red[4 + grp][tl] = sq;
  __syncthreads();
  if (tid < 64) {
    float su = red[0][tid] + red[1][tid] + red[2][tid] + red[3][tid];
    float sqq = red[4][tid] + red[5][tid] + red[6][tid] + red[7][tid];
    float m = su * (1.f / Cz);
    float var = sqq * (1.f / Cz) - m * m;
    ms[tid] = m;
    rs[tid] = rsqrtf(var + 1e-5f);
  }
  __syncthreads();
  float m = ms[tl], r = rs[tl];
  for (int c = grp; c < Cz; c += 4) {
    float v = x[bx + (size_t)c * TS] + y[by + (size_t)c * Tz];
    x[bx + (size_t)c * TS] = (v - m) * r * g[c] + bb[c];
  }
}

// ---------------------------------------------------------------------------
extern "C" void kernel_launch(void* const* d_in, const int* in_sizes, int n_in,
                              void* d_out, int out_size, void* d_ws,
                              size_t ws_size, hipStream_t stream) {
  const float* x = (const float*)d_in[0];
  const float* xm = (const float*)d_in[1];
  const float* wq = (const float*)d_in[2];
  const float* bq = (const float*)d_in[3];
  const float* wk = (const float*)d_in[4];
  const float* bk = (const float*)d_in[5];
  const float* wv = (const float*)d_in[6];
  const float* bv = (const float*)d_in[7];
  const float* wo = (const float*)d_in[8];
  const float* bo = (const float*)d_in[9];
  const float* erk = (const float*)d_in[10];
  const float* erv = (const float*)d_in[11];
  const float* g1 = (const float*)d_in[12];
  const float* b1 = (const float*)d_in[13];
  const float* fw1 = (const float*)d_in[14];
  const float* fb1 = (const float*)d_in[15];
  const float* fw2 = (const float*)d_in[16];
  const float* fb2 = (const float*)d_in[17];
  const float* g2 = (const float*)d_in[18];
  const float* b2 = (const float*)d_in[19];

  const size_t NBC = (size_t)Bz * Cz * Tz;       // 1,048,576
  const size_t XBN = (size_t)Bz * Cz * TS;       // 1,056,768
  const size_t HP = (size_t)Bz * PROWS * FCz;    // 4,202,496 (u16 per array)
  const size_t XP = (size_t)Bz * PROWS * Cz;     // 1,050,624 (u16 per array)
  const size_t WPC = (size_t)3 * 1024 * 256;     // 786,432 (u16 per array)

  float* ws = (float*)d_ws;
  float* xb = ws;                       // padded fp32 activation
  float* yb = xb + XBN;                 // fp32 residual branch
  float* un = yb + NBC;                 // union: q/k/v/ao  OR  h' packed
  float* qb = un;
  float* kb = un + NBC;
  float* vb = un + 2 * NBC;
  float* aob = un + 3 * NBC;
  u16* hpH = (u16*)un;                  // h' hi [B][1026][FC]
  u16* hpL = hpH + HP;                  // h' lo
  float* xpf = un + (2 * HP + 3) / 2;   // = un + HP (floats) ; x'/ao' packed
  u16* xpH = (u16*)xpf;
  u16* xpL = xpH + XP;
  float* wp = xpf + XP;                 // XP u16*2 = XP floats
  u16* wpH = (u16*)wp;
  u16* wpL = wpH + WPC;
  float* pbias = wp + WPC;              // WPC u16*2 = WPC floats

  const int ntot = (int)NBC;
  mask_in<<<dim3((ntot + 255) / 256), 256, 0, stream>>>(x, xm, xb);
  zero_halo<<<dim3((Bz * 2 * Cz + 255) / 256), 256, 0, stream>>>(xpH, xpL, Cz);
  // initial x' for layer-0 qkv (xb already masked; binary mask assumed)
  tpack<<<dim3(16, 4, 4), 256, 0, stream>>>(xb, TS, PADF, xm, 1, xpH, xpL, Cz);

  for (int l = 0; l < Lz; l++) {
    pack_qkvwo<<<dim3(1024, 1, 1), 256, 0, stream>>>(
        wq + (size_t)l * Cz * Cz, wk + (size_t)l * Cz * Cz,
        wv + (size_t)l * Cz * Cz, wo + (size_t)l * Cz * Cz, bq + l * Cz,
        bk + l * Cz, bv + l * Cz, bo + l * Cz, wpH, wpL, pbias);
    mfma_gemm<1, 0><<<dim3(16, 12, 4), 256, 0, stream>>>(
        wpH, wpL, xpH, xpL, pbias, xm, qb, kb, vb, nullptr, 0, 0, nullptr,
        nullptr, 1024, Cz, 0);
    attn_kernel<<<dim3(16, 16), dim3(16, 16), 0, stream>>>(
        qb, kb, vb, xm, erk + l * NR * KCz, erv + l * NR * KCz, aob);
    // pack attention output for wo (no mask)
    tpack<<<dim3(16, 4, 4), 256, 0, stream>>>(aob, Tz, 0, xm, 0, xpH, xpL, Cz);
    mfma_gemm<1, 1><<<dim3(16, 4, 4), 256, 0, stream>>>(
        wpH, wpL, xpH, xpL, pbias, xm, nullptr, nullptr, nullptr, yb, 768, 0,
        nullptr, nullptr, 1024, Cz, 768);
    add_ln<<<dim3(16, 4), 256, 0, stream>>>(xb, yb, g1 + l * Cz, b1 + l * Cz);
    // x' for conv1 (mask applied)
    tpack<<<dim3(16, 4, 4), 256, 0, stream>>>(xb, TS, PADF, xm, 1, xpH, xpL,
                                              Cz);
    zero_halo<<<dim3((Bz * 2 * FCz + 255) / 256), 256, 0, stream>>>(hpH, hpL,
                                                                    FCz);
    pack_w3<<<dim3((3 * FCz * Cz + 255) / 256), 256, 0, stream>>>(
        fw1 + (size_t)l * FCz * Cz * 3, wpH, wpL, FCz, Cz);
    mfma_gemm<3, 2><<<dim3(16, 16, 4), 256, 0, stream>>>(
        wpH, wpL, xpH, xpL, fb1 + l * FCz, xm, nullptr, nullptr, nullptr,
        nullptr, 0, 0, hpH, hpL, FCz, Cz, 0);
    pack_w3<<<dim3((3 * Cz * FCz + 255) / 256), 256, 0, stream>>>(
        fw2 + (size_t)l * Cz * FCz * 3, wpH, wpL, Cz, FCz);
    mfma_gemm<3, 1><<<dim3(16, 4, 4), 256, 0, stream>>>(
        wpH, wpL, hpH, hpL, fb2 + l * Cz, xm, nullptr, nullptr, nullptr, yb, 0,
        1, nullptr, nullptr, Cz, FCz, 0);
    add_ln<<<dim3(16, 4), 256, 0, stream>>>(xb, yb, g2 + l * Cz, b2 + l * Cz);
    // x' for next layer's qkv
    tpack<<<dim3(16, 4, 4), 256, 0, stream>>>(xb, TS, PADF, xm, 1, xpH, xpL,
                                              Cz);
  }
  mask_out<<<dim3((ntot + 255) / 256), 256, 0, stream>>>(xb, xm,
                                                         (float*)d_out);
}

// Round 5
// 1622.575 us; speedup vs baseline: 3.4464x; 1.5132x over previous
//
#include <hip/hip_runtime.h>

// Encoder: L=6 layers of (rel-pos attention + channel-LN + K=3 conv FFN + LN)
// B=4, C=256, T=1024, H=4, KC=64, FC=1024, W=10, fp32 I/O.
// All heavy math via split-bf16 (hi/lo) emulated-fp32 MFMA
// (3 passes of mfma_f32_16x16x32_bf16), including attention.

#define Lz 6
#define Cz 256
#define FCz 1024
#define Hz 4
#define Wz 10
#define Bz 4
#define Tz 1024
#define KCz 64
#define NR 21
#define TS 1032  // padded fp32 activation row stride
#define PADF 4
#define PROWS 1026  // packed channel-last rows: 1 halo + 1024 + 1 halo

typedef unsigned short u16;
typedef unsigned int u32;
typedef __attribute__((ext_vector_type(8))) short bf8v;   // 8 bf16 = 4 VGPR
typedef __attribute__((ext_vector_type(4))) float f4v;

#define MFMA(a, b, c) __builtin_amdgcn_mfma_f32_16x16x32_bf16(a, b, c, 0, 0, 0)

__device__ inline void bf_split(float v, u16& hi, u16& lo) {
  unsigned u = __float_as_uint(v);
  unsigned hr = (u + 0x7FFFu + ((u >> 16) & 1u)) >> 16;
  float rem = v - __uint_as_float(hr << 16);
  unsigned u2 = __float_as_uint(rem);
  unsigned lr = (u2 + 0x7FFFu + ((u2 >> 16) & 1u)) >> 16;
  hi = (u16)hr;
  lo = (u16)lr;
}

// ---------------------------------------------------------------------------
__global__ __launch_bounds__(256) void mask_in(const float* __restrict__ x,
                                               const float* __restrict__ m,
                                               float* __restrict__ xp) {
  int id = blockIdx.x * 256 + threadIdx.x;
  if (id < Bz * Cz * Tz) {
    int t = id & (Tz - 1), row = id >> 10, b = id >> 18;
    xp[(size_t)row * TS + PADF + t] = x[id] * m[b * Tz + t];
  }
}

__global__ __launch_bounds__(256) void mask_out(const float* __restrict__ xp,
                                                const float* __restrict__ m,
                                                float* __restrict__ out) {
  int id = blockIdx.x * 256 + threadIdx.x;
  if (id < Bz * Cz * Tz) {
    int t = id & (Tz - 1), row = id >> 10, b = id >> 18;
    out[id] = xp[(size_t)row * TS + PADF + t] * m[b * Tz + t];
  }
}

// zero halo rows (0 and 1025) of packed [B][1026][Cd] hi/lo pair
__global__ __launch_bounds__(256) void zero_halo(u16* hi, u16* lo, int Cd) {
  int id = blockIdx.x * 256 + threadIdx.x;
  if (id >= Bz * 2 * Cd) return;
  int c = id % Cd, rb = id / Cd, b = rb >> 1, s = rb & 1;
  size_t a = ((size_t)b * PROWS + (s ? (PROWS - 1) : 0)) * Cd + c;
  hi[a] = 0;
  lo[a] = 0;
}

// ---------------------------------------------------------------------------
// Transpose-pack: fp32 [b][Cd][sstride(+soff)] -> bf16 hi/lo [b][1026][Cd]
// ---------------------------------------------------------------------------
__global__ __launch_bounds__(256) void tpack(const float* __restrict__ src,
                                             int sstride, int soff,
                                             const float* __restrict__ mask,
                                             int amask, u16* __restrict__ dhi,
                                             u16* __restrict__ dlo, int Cd) {
  __shared__ float L[64 * 68];
  const int tid = threadIdx.x;
  const int t0 = blockIdx.x * 64, c0 = blockIdx.y * 64, b = blockIdx.z;
  const float* sb = src + (size_t)b * Cd * sstride + soff;
#pragma unroll
  for (int i = 0; i < 16; i++) {
    int id = tid + 256 * i;
    int cc = id >> 6, tt = id & 63;
    L[cc * 68 + tt] = sb[(size_t)(c0 + cc) * sstride + t0 + tt];
  }
  __syncthreads();
  const int tt = tid >> 2, p = tid & 3;
  float mv = amask ? mask[(size_t)b * Tz + t0 + tt] : 1.f;
  u16 hs[16], ls[16];
#pragma unroll
  for (int j = 0; j < 16; j++) {
    float v = L[(p * 16 + j) * 68 + tt] * mv;
    bf_split(v, hs[j], ls[j]);
  }
  size_t da = ((size_t)b * PROWS + t0 + tt + 1) * Cd + c0 + p * 16;
  *(uint4*)&dhi[da] = *(uint4*)&hs[0];
  *(uint4*)&dhi[da + 8] = *(uint4*)&hs[8];
  *(uint4*)&dlo[da] = *(uint4*)&ls[0];
  *(uint4*)&dlo[da + 8] = *(uint4*)&ls[8];
}

// ---------------------------------------------------------------------------
// Pack q,k,v,o weights into A[1024][256] hi/lo + concatenated bias[1024].
// ---------------------------------------------------------------------------
__global__ __launch_bounds__(256) void pack_qkvwo(
    const float* __restrict__ wq, const float* __restrict__ wk,
    const float* __restrict__ wv, const float* __restrict__ wo_,
    const float* __restrict__ bq, const float* __restrict__ bk,
    const float* __restrict__ bv, const float* __restrict__ bo,
    u16* __restrict__ hi, u16* __restrict__ lo, float* __restrict__ pb) {
  int id = blockIdx.x * 256 + threadIdx.x;
  if (id >= 1024 * 256) return;
  int o = id >> 8, c = id & 255;
  int sel = o >> 8;
  const float* w = sel == 0 ? wq : (sel == 1 ? wk : (sel == 2 ? wv : wo_));
  float v = w[((size_t)(o & 255) << 8) + c];
  bf_split(v, hi[id], lo[id]);
  if (id < 1024) {
    int s2 = id >> 8;
    const float* bs = s2 == 0 ? bq : (s2 == 1 ? bk : (s2 == 2 ? bv : bo));
    pb[id] = bs[id & 255];
  }
}

// Pack conv weights fw[Cout][Cin][3] -> A[tap][Cout][Cin] hi/lo.
__global__ __launch_bounds__(256) void pack_w3(const float* __restrict__ fw,
                                               u16* __restrict__ hi,
                                               u16* __restrict__ lo, int Cout,
                                               int Cin) {
  int id = blockIdx.x * 256 + threadIdx.x;
  if (id >= 3 * Cout * Cin) return;
  int c = id % Cin, rest = id / Cin;
  int o = rest % Cout, tap = rest / Cout;
  float v = fw[((size_t)o * Cin + c) * 3 + tap];
  bf_split(v, hi[id], lo[id]);
}

// Pack erk -> [32 r][64 d] hi/lo (rows>=21 zero); erv -> [64 d][32 r] hi/lo.
__global__ __launch_bounds__(256) void pack_er(const float* __restrict__ erk,
                                               const float* __restrict__ erv,
                                               u16* __restrict__ ekH,
                                               u16* __restrict__ ekL,
                                               u16* __restrict__ evH,
                                               u16* __restrict__ evL) {
  int id = blockIdx.x * 256 + threadIdx.x;
  if (id < 2048) {
    int rr = id >> 6, d = id & 63;
    float v = (rr < NR) ? erk[rr * KCz + d] : 0.f;
    bf_split(v, ekH[id], ekL[id]);
  } else if (id < 4096) {
    int id2 = id - 2048;
    int d = id2 >> 5, rr = id2 & 31;
    float v = (rr < NR) ? erv[rr * KCz + d] : 0.f;
    bf_split(v, evH[id2], evL[id2]);
  }
}

// ---------------------------------------------------------------------------
// Split-bf16 MFMA GEMM: D[m][t] = sum_{tap,c} A[tap][m][c] * Bp[t+tap][c]
// Block tile 64m x 64t, 4 waves of 32x32, K-tile 32; 3 mfma passes per tile.
// EPI 0: qkv -> packed bf16 hi/lo Q[b][h][t][d] (x0.125), K[b][h][t][d],
//        V[b][h][d][t], routed by m0>>8.
// EPI 1: out fp32 [b][256][Tz] rows (m - out_moff), optional mask.
// EPI 2: relu + mask, split -> packed hi/lo [B][1026][M] rows +1 (conv1).
// ---------------------------------------------------------------------------
template <int TAPS, int EPI>
__global__ __launch_bounds__(256) void mfma_gemm(
    const u16* __restrict__ Ah, const u16* __restrict__ Al,
    const u16* __restrict__ Bh, const u16* __restrict__ Bl,
    const float* __restrict__ bias, const float* __restrict__ mask,
    float* __restrict__ out, int out_moff, int amask, u16* __restrict__ ph,
    u16* __restrict__ pl, u16* __restrict__ pqh, u16* __restrict__ pql,
    u16* __restrict__ pkh, u16* __restrict__ pkl, u16* __restrict__ pvh,
    u16* __restrict__ pvl, int M, int Kc, int m_base) {
  __shared__ u16 sm[4 * 64 * 40];  // Ash, Asl, Bsh, Bsl
  u16* Ash = sm;
  u16* Asl = sm + 2560;
  u16* Bsh = sm + 5120;
  u16* Bsl = sm + 7680;
  const int tid = threadIdx.x;
  const int lane = tid & 63, wid = tid >> 6;
  const int wm = wid & 1, wn = wid >> 1;
  const int r = lane & 15, qd = lane >> 4;
  const int t0 = blockIdx.x * 64;
  const int m0 = blockIdx.y * 64 + m_base;
  const int b = blockIdx.z;
  const int srow = tid >> 2, sseg = (tid & 3) * 8;

  f4v acc[2][2];
#pragma unroll
  for (int i = 0; i < 2; i++)
#pragma unroll
    for (int j = 0; j < 2; j++) acc[i][j] = (f4v)(0.f);

  for (int tap = 0; tap < TAPS; tap++) {
    const u16* Ath = Ah + (size_t)tap * M * Kc;
    const u16* Atl = Al + (size_t)tap * M * Kc;
    const int tofs = (TAPS == 1) ? 1 : tap;
    const size_t arow = (size_t)(m0 + srow) * Kc;
    const size_t brow = ((size_t)b * PROWS + t0 + tofs + srow) * Kc;
    for (int kc = 0; kc < Kc; kc += 32) {
      *(uint4*)&Ash[srow * 40 + sseg] = *(const uint4*)&Ath[arow + kc + sseg];
      *(uint4*)&Asl[srow * 40 + sseg] = *(const uint4*)&Atl[arow + kc + sseg];
      *(uint4*)&Bsh[srow * 40 + sseg] = *(const uint4*)&Bh[brow + kc + sseg];
      *(uint4*)&Bsl[srow * 40 + sseg] = *(const uint4*)&Bl[brow + kc + sseg];
      __syncthreads();
      bf8v ah[2], al[2], bh[2], bl[2];
#pragma unroll
      for (int f = 0; f < 2; f++) {
        int ar = (wm * 32 + f * 16 + r) * 40 + qd * 8;
        int br = (wn * 32 + f * 16 + r) * 40 + qd * 8;
        ah[f] = *(bf8v*)&Ash[ar];
        al[f] = *(bf8v*)&Asl[ar];
        bh[f] = *(bf8v*)&Bsh[br];
        bl[f] = *(bf8v*)&Bsl[br];
      }
#pragma unroll
      for (int mf = 0; mf < 2; mf++)
#pragma unroll
        for (int nf = 0; nf < 2; nf++) {
          acc[mf][nf] = MFMA(ah[mf], bh[nf], acc[mf][nf]);
          acc[mf][nf] = MFMA(al[mf], bh[nf], acc[mf][nf]);
          acc[mf][nf] = MFMA(ah[mf], bl[nf], acc[mf][nf]);
        }
      __syncthreads();
    }
  }

  float* Ds = (float*)sm;  // 64x68 fp32 staging
  if constexpr (EPI == 0) {
    const int sel = m0 >> 8;  // 0 q, 1 k, 2 v
    const int h = (m0 >> 6) & 3;
    const int bhI = b * Hz + h;
    if (sel < 2) {
      // transposed staging Ds[n][m] -> write [t][d] packed
#pragma unroll
      for (int mf = 0; mf < 2; mf++)
#pragma unroll
        for (int nf = 0; nf < 2; nf++) {
          int nl = wn * 32 + nf * 16 + r;
          int ml = wm * 32 + mf * 16 + qd * 4;
          *(f4v*)&Ds[nl * 68 + ml] = acc[mf][nf];
        }
      __syncthreads();
      const int row = tid >> 2, p = tid & 3;
      const float scq = (sel == 0) ? 0.125f : 1.f;
      u16 hs[16], ls[16];
#pragma unroll
      for (int jj = 0; jj < 4; jj++) {
        float4 dv = *(float4*)&Ds[row * 68 + p * 16 + jj * 4];
        float4 bb = *(const float4*)&bias[m0 + p * 16 + jj * 4];
        float vv[4] = {(dv.x + bb.x) * scq, (dv.y + bb.y) * scq,
                       (dv.z + bb.z) * scq, (dv.w + bb.w) * scq};
#pragma unroll
        for (int e = 0; e < 4; e++)
          bf_split(vv[e], hs[jj * 4 + e], ls[jj * 4 + e]);
      }
      u16* oh = (sel == 0) ? pqh : pkh;
      u16* ol = (sel == 0) ? pql : pkl;
      size_t da = ((size_t)bhI * Tz + t0 + row) * KCz + p * 16;
      *(uint4*)&oh[da] = *(uint4*)&hs[0];
      *(uint4*)&oh[da + 8] = *(uint4*)&hs[8];
      *(uint4*)&ol[da] = *(uint4*)&ls[0];
      *(uint4*)&ol[da + 8] = *(uint4*)&ls[8];
    } else {
      // normal staging Ds[m][n] -> write V [d][t] packed
#pragma unroll
      for (int mf = 0; mf < 2; mf++)
#pragma unroll
        for (int nf = 0; nf < 2; nf++) {
          int ml = wm * 32 + mf * 16 + qd * 4;
          int nl = wn * 32 + nf * 16 + r;
#pragma unroll
          for (int e = 0; e < 4; e++) Ds[(ml + e) * 68 + nl] = acc[mf][nf][e];
        }
      __syncthreads();
      const int row = tid >> 2, p = tid & 3;
      const float bb = bias[m0 + row];
      u16 hs[16], ls[16];
#pragma unroll
      for (int jj = 0; jj < 16; jj++)
        bf_split(Ds[row * 68 + p * 16 + jj] + bb, hs[jj], ls[jj]);
      size_t da = ((size_t)bhI * KCz + row) * Tz + t0 + p * 16;
      *(uint4*)&pvh[da] = *(uint4*)&hs[0];
      *(uint4*)&pvh[da + 8] = *(uint4*)&hs[8];
      *(uint4*)&pvl[da] = *(uint4*)&ls[0];
      *(uint4*)&pvl[da + 8] = *(uint4*)&ls[8];
    }
  } else if constexpr (EPI == 2) {
    // Ds[n][m]
#pragma unroll
    for (int mf = 0; mf < 2; mf++)
#pragma unroll
      for (int nf = 0; nf < 2; nf++) {
        int nl = wn * 32 + nf * 16 + r;
        int ml = wm * 32 + mf * 16 + qd * 4;
        *(f4v*)&Ds[nl * 68 + ml] = acc[mf][nf];
      }
    __syncthreads();
    const int row = tid >> 2, p = tid & 3;
    const int t = t0 + row;
    float mv = mask[(size_t)b * Tz + t];
    u16 hs[16], ls[16];
#pragma unroll
    for (int jj = 0; jj < 4; jj++) {
      float4 dv = *(float4*)&Ds[row * 68 + p * 16 + jj * 4];
      float4 bb = *(const float4*)&bias[m0 + p * 16 + jj * 4];
      float vv[4] = {dv.x + bb.x, dv.y + bb.y, dv.z + bb.z, dv.w + bb.w};
#pragma unroll
      for (int e = 0; e < 4; e++) {
        float v = fmaxf(vv[e], 0.f) * mv;
        bf_split(v, hs[jj * 4 + e], ls[jj * 4 + e]);
      }
    }
    size_t da = ((size_t)b * PROWS + t + 1) * M + m0 + p * 16;
    *(uint4*)&ph[da] = *(uint4*)&hs[0];
    *(uint4*)&ph[da + 8] = *(uint4*)&hs[8];
    *(uint4*)&pl[da] = *(uint4*)&ls[0];
    *(uint4*)&pl[da + 8] = *(uint4*)&ls[8];
  } else {
    // EPI 1: Ds[m][n]
#pragma unroll
    for (int mf = 0; mf < 2; mf++)
#pragma unroll
      for (int nf = 0; nf < 2; nf++) {
        int ml = wm * 32 + mf * 16 + qd * 4;
        int nl = wn * 32 + nf * 16 + r;
#pragma unroll
        for (int e = 0; e < 4; e++) Ds[(ml + e) * 68 + nl] = acc[mf][nf][e];
      }
    __syncthreads();
    const int row = tid >> 2, p = tid & 3;
    const int m = m0 + row;
    const float bb = bias[m];
    size_t oa = ((size_t)b * Cz + (m - out_moff)) * Tz + t0 + p * 16;
#pragma unroll
    for (int jj = 0; jj < 4; jj++) {
      float4 dv = *(float4*)&Ds[row * 68 + p * 16 + jj * 4];
      float4 rv = make_float4(dv.x + bb, dv.y + bb, dv.z + bb, dv.w + bb);
      if (amask) {
        float4 mk = *(const float4*)&mask[(size_t)b * Tz + t0 + p * 16 + jj * 4];
        rv.x *= mk.x; rv.y *= mk.y; rv.z *= mk.z; rv.w *= mk.w;
      }
      *(float4*)&out[oa + jj * 4] = rv;
    }
  }
}

// ---------------------------------------------------------------------------
// MFMA flash attention with banded rel-pos. Inputs packed bf16 hi/lo:
// Q(x0.125),K [b][h][t][d]; V [b][h][d][t]. Output: packed hi/lo
// [B][1026][256] rows+1 (the wo-GEMM's B layout). grid (16 i-tiles, B*H).
// Each of 4 waves owns 16 q-rows; per j-tile: S via 3-pass MFMA, online
// softmax (quad shuffles), P->LDS packed u32, PV via 3-pass MFMA.
// ---------------------------------------------------------------------------
__global__ __launch_bounds__(256) void attn_mfma(
    const u16* __restrict__ Qh_, const u16* __restrict__ Ql_,
    const u16* __restrict__ Kh_, const u16* __restrict__ Kl_,
    const u16* __restrict__ Vh_, const u16* __restrict__ Vl_,
    const float* __restrict__ mask, const u16* __restrict__ erkH,
    const u16* __restrict__ erkL, const u16* __restrict__ ervH,
    const u16* __restrict__ ervL, u16* __restrict__ outH,
    u16* __restrict__ outL) {
  __shared__ __align__(16) char smraw[64768];
  u16* Ksh = (u16*)smraw;                       // [64][72]
  u16* Ksl = Ksh + 64 * 72;
  u16* Vsh = Ksl + 64 * 72;                     // [64][72] (V^T: [d][j])
  u16* Vsl = Vsh + 64 * 72;                     // end 36864 B
  u32* Psp = (u32*)(smraw + 36864);             // [64][66] packed P -> 16896 B
  float* rqs = (float*)(smraw + 53760);         // [64][21] -> 5376 B
  float* bands = (float*)(smraw + 59136);       // [64][21] -> 5376 B
  float* mrowS = (float*)(smraw + 64512);       // [64]

  const int tid = threadIdx.x;
  const int lane = tid & 63, wid = tid >> 6;
  const int r = lane & 15, qd = lane >> 4;
  const int iw = wid * 16;
  const int i0 = blockIdx.x * 64;
  const int bh = blockIdx.y;
  const int b = bh >> 2, h = bh & 3;
  const float* mb = mask + (size_t)b * Tz;
  const size_t qkbase = (size_t)bh * Tz * KCz;
  const size_t vbase = (size_t)bh * KCz * Tz;

  // Q fragments (rows i0+iw+r), resident in registers for the whole kernel
  bf8v qh[2], ql[2];
  {
    const size_t qrow = qkbase + (size_t)(i0 + iw + r) * KCz;
#pragma unroll
    for (int ks = 0; ks < 2; ks++) {
      qh[ks] = *(const bf8v*)&Qh_[qrow + ks * 32 + qd * 8];
      ql[ks] = *(const bf8v*)&Ql_[qrow + ks * 32 + qd * 8];
    }
  }
  for (int id = tid; id < 64 * NR; id += 256) bands[id] = -1e30f;

  // rq[i][rr] = q^ . erk  via MFMA (rows iw..iw+15 wave-local)
  {
    f4v rc[2] = {(f4v)(0.f), (f4v)(0.f)};
#pragma unroll
    for (int nf = 0; nf < 2; nf++)
#pragma unroll
      for (int ks = 0; ks < 2; ks++) {
        bf8v eh = *(const bf8v*)&erkH[(16 * nf + r) * 64 + ks * 32 + qd * 8];
        bf8v el = *(const bf8v*)&erkL[(16 * nf + r) * 64 + ks * 32 + qd * 8];
        rc[nf] = MFMA(qh[ks], eh, rc[nf]);
        rc[nf] = MFMA(ql[ks], eh, rc[nf]);
        rc[nf] = MFMA(qh[ks], el, rc[nf]);
      }
#pragma unroll
    for (int nf = 0; nf < 2; nf++) {
      int rr = 16 * nf + r;
      if (rr < NR) {
#pragma unroll
        for (int e = 0; e < 4; e++)
          rqs[(iw + 4 * qd + e) * NR + rr] = rc[nf][e];
      }
    }
  }

  float qm4[4];
#pragma unroll
  for (int e = 0; e < 4; e++) qm4[e] = mb[i0 + iw + 4 * qd + e];

  float m_st[4] = {-1e30f, -1e30f, -1e30f, -1e30f};
  float l_st[4] = {0.f, 0.f, 0.f, 0.f};
  f4v oacc[4];
#pragma unroll
  for (int nf = 0; nf < 4; nf++) oacc[nf] = (f4v)(0.f);
  __syncthreads();

  for (int j0t = 0; j0t < 16; j0t++) {
    const int j0 = j0t * 64;
    __syncthreads();  // prev tile's K/V reads complete
    {
      const int row = tid >> 2, seg = (tid & 3) * 16;
      const size_t krow = qkbase + (size_t)(j0 + row) * KCz + seg;
      const size_t vrow = vbase + (size_t)row * Tz + j0 + seg;
      *(uint4*)&Ksh[row * 72 + seg] = *(const uint4*)&Kh_[krow];
      *(uint4*)&Ksh[row * 72 + seg + 8] = *(const uint4*)&Kh_[krow + 8];
      *(uint4*)&Ksl[row * 72 + seg] = *(const uint4*)&Kl_[krow];
      *(uint4*)&Ksl[row * 72 + seg + 8] = *(const uint4*)&Kl_[krow + 8];
      *(uint4*)&Vsh[row * 72 + seg] = *(const uint4*)&Vh_[vrow];
      *(uint4*)&Vsh[row * 72 + seg + 8] = *(const uint4*)&Vh_[vrow + 8];
      *(uint4*)&Vsl[row * 72 + seg] = *(const uint4*)&Vl_[vrow];
      *(uint4*)&Vsl[row * 72 + seg + 8] = *(const uint4*)&Vl_[vrow + 8];
    }
    __syncthreads();

    // S = q^ K^T (3-pass)
    f4v sa[4];
#pragma unroll
    for (int nf = 0; nf < 4; nf++) sa[nf] = (f4v)(0.f);
#pragma unroll
    for (int nf = 0; nf < 4; nf++)
#pragma unroll
      for (int ks = 0; ks < 2; ks++) {
        bf8v kh = *(bf8v*)&Ksh[(16 * nf + r) * 72 + ks * 32 + qd * 8];
        bf8v kl = *(bf8v*)&Ksl[(16 * nf + r) * 72 + ks * 32 + qd * 8];
        sa[nf] = MFMA(qh[ks], kh, sa[nf]);
        sa[nf] = MFMA(ql[ks], kh, sa[nf]);
        sa[nf] = MFMA(qh[ks], kl, sa[nf]);
      }

    // bias + mask + band capture + row max
    float km4[4];
#pragma unroll
    for (int nf = 0; nf < 4; nf++) km4[nf] = mb[j0 + 16 * nf + r];
    float rmax[4] = {-1e30f, -1e30f, -1e30f, -1e30f};
    float sv[4][4];
#pragma unroll
    for (int nf = 0; nf < 4; nf++)
#pragma unroll
      for (int e = 0; e < 4; e++) {
        int ii = iw + 4 * qd + e;
        int dl = (j0 + 16 * nf + r) - (i0 + ii);
        float s = sa[nf][e];
        bool inb = (unsigned)(dl + Wz) <= 2u * Wz;
        if (inb) s += rqs[ii * NR + dl + Wz];
        if (qm4[e] * km4[nf] == 0.f) s = -1e4f;
        if (inb) bands[ii * NR + dl + Wz] = s;
        sv[nf][e] = s;
        rmax[e] = fmaxf(rmax[e], s);
      }
#pragma unroll
    for (int off = 1; off < 16; off <<= 1)
#pragma unroll
      for (int e = 0; e < 4; e++)
        rmax[e] = fmaxf(rmax[e], __shfl_xor(rmax[e], off, 16));

    float al[4], psum[4];
#pragma unroll
    for (int e = 0; e < 4; e++) {
      float mn = fmaxf(m_st[e], rmax[e]);
      al[e] = __expf(m_st[e] - mn);
      m_st[e] = mn;
      l_st[e] *= al[e];
      psum[e] = 0.f;
    }
    // P = exp(S - m), write packed to LDS (own rows only)
#pragma unroll
    for (int nf = 0; nf < 4; nf++)
#pragma unroll
      for (int e = 0; e < 4; e++) {
        float p = __expf(sv[nf][e] - m_st[e]);
        psum[e] += p;
        u16 hi, lo;
        bf_split(p, hi, lo);
        Psp[(iw + 4 * qd + e) * 66 + 16 * nf + r] = (u32)hi | ((u32)lo << 16);
      }
#pragma unroll
    for (int off = 1; off < 16; off <<= 1)
#pragma unroll
      for (int e = 0; e < 4; e++) psum[e] += __shfl_xor(psum[e], off, 16);
#pragma unroll
    for (int e = 0; e < 4; e++) l_st[e] += psum[e];
#pragma unroll
    for (int nf = 0; nf < 4; nf++)
#pragma unroll
      for (int e = 0; e < 4; e++) oacc[nf][e] *= al[e];

    // O += P V (wave reads only its own P rows; no barrier needed)
#pragma unroll
    for (int ks = 0; ks < 2; ks++) {
      u32 w8[8];
      const u32* pp = &Psp[(iw + r) * 66 + ks * 32 + qd * 8];
#pragma unroll
      for (int k2 = 0; k2 < 4; k2++) {
        uint2 t2 = *(uint2*)&pp[2 * k2];
        w8[2 * k2] = t2.x;
        w8[2 * k2 + 1] = t2.y;
      }
      union { bf8v v; u32 u[4]; } Ph, Pl;
#pragma unroll
      for (int k2 = 0; k2 < 4; k2++) {
        Ph.u[k2] = (w8[2 * k2] & 0xffffu) | (w8[2 * k2 + 1] << 16);
        Pl.u[k2] = (w8[2 * k2] >> 16) | (w8[2 * k2 + 1] & 0xffff0000u);
      }
#pragma unroll
      for (int nf = 0; nf < 4; nf++) {
        bf8v vh = *(bf8v*)&Vsh[(16 * nf + r) * 72 + ks * 32 + qd * 8];
        bf8v vl = *(bf8v*)&Vsl[(16 * nf + r) * 72 + ks * 32 + qd * 8];
        oacc[nf] = MFMA(Ph.v, vh, oacc[nf]);
        oacc[nf] = MFMA(Pl.v, vh, oacc[nf]);
        oacc[nf] = MFMA(Ph.v, vl, oacc[nf]);
      }
    }
  }

  if (r == 0) {
#pragma unroll
    for (int e = 0; e < 4; e++) mrowS[iw + 4 * qd + e] = m_st[e];
  }
  __syncthreads();

  // band probs -> packed bf16 [64][36] (reusing Psp region)
  u32* bandsP = Psp;
  for (int id = tid; id < 64 * 32; id += 256) {
    int i = id >> 5, rr = id & 31;
    float p = (rr < NR) ? __expf(bands[i * NR + rr] - mrowS[i]) : 0.f;
    u16 hi, lo;
    bf_split(p, hi, lo);
    bandsP[i * 36 + rr] = (u32)hi | ((u32)lo << 16);
  }
  __syncthreads();

  // O += bandP . erv  (rel-V) via MFMA
  {
    u32 w8[8];
    const u32* pp = &bandsP[(iw + r) * 36 + qd * 8];
#pragma unroll
    for (int k2 = 0; k2 < 2; k2++) {
      uint4 t4 = *(uint4*)&pp[4 * k2];
      w8[4 * k2] = t4.x; w8[4 * k2 + 1] = t4.y;
      w8[4 * k2 + 2] = t4.z; w8[4 * k2 + 3] = t4.w;
    }
    union { bf8v v; u32 u[4]; } Ph, Pl;
#pragma unroll
    for (int k2 = 0; k2 < 4; k2++) {
      Ph.u[k2] = (w8[2 * k2] & 0xffffu) | (w8[2 * k2 + 1] << 16);
      Pl.u[k2] = (w8[2 * k2] >> 16) | (w8[2 * k2 + 1] & 0xffff0000u);
    }
#pragma unroll
    for (int nf = 0; nf < 4; nf++) {
      bf8v eh = *(const bf8v*)&ervH[(16 * nf + r) * 32 + qd * 8];
      bf8v el = *(const bf8v*)&ervL[(16 * nf + r) * 32 + qd * 8];
      oacc[nf] = MFMA(Ph.v, eh, oacc[nf]);
      oacc[nf] = MFMA(Pl.v, eh, oacc[nf]);
      oacc[nf] = MFMA(Ph.v, el, oacc[nf]);
    }
  }

  // normalize, stage O[i][d], pack out
  float* Os = (float*)smraw;  // [64][68]
  float linv[4];
#pragma unroll
  for (int e = 0; e < 4; e++) linv[e] = 1.f / l_st[e];
#pragma unroll
  for (int nf = 0; nf < 4; nf++)
#pragma unroll
    for (int e = 0; e < 4; e++)
      Os[(iw + 4 * qd + e) * 68 + 16 * nf + r] = oacc[nf][e] * linv[e];
  __syncthreads();
  {
    const int row = tid >> 2, p = tid & 3;
    const float* src = &Os[row * 68 + p * 16];
    u16 hs[16], ls[16];
#pragma unroll
    for (int j = 0; j < 16; j++) bf_split(src[j], hs[j], ls[j]);
    size_t da = ((size_t)b * PROWS + i0 + row + 1) * Cz + h * 64 + p * 16;
    *(uint4*)&outH[da] = *(uint4*)&hs[0];
    *(uint4*)&outH[da + 8] = *(uint4*)&hs[8];
    *(uint4*)&outL[da] = *(uint4*)&ls[0];
    *(uint4*)&outL[da + 8] = *(uint4*)&ls[8];
  }
}

// ---------------------------------------------------------------------------
// In-place residual + channel LayerNorm: x(padded) = LN(x + y)*g + b
// ---------------------------------------------------------------------------
__global__ __launch_bounds__(256) void add_ln(float* __restrict__ x,
                                              const float* __restrict__ y,
                                              const float* __restrict__ g,
                                              const float* __restrict__ bb) {
  __shared__ float red[8][64];
  __shared__ float ms[64], rs[64];
  const int tid = threadIdx.x;
  const int t0 = blockIdx.x * 64, b = blockIdx.y;
  const int tl = tid & 63, grp = tid >> 6;
  const size_t bx = (size_t)b * Cz * TS + PADF + t0 + tl;
  const size_t by = (size_t)b * Cz * Tz + t0 + tl;
  float s = 0.f, sq = 0.f;
  for (int c = grp; c < Cz; c += 4) {
    float v = x[bx + (size_t)c * TS] + y[by + (size_t)c * Tz];
    s += v;
    sq += v * v;
  }
  red[grp][tl] = s;
  red[4 + grp][tl] = sq;
  __syncthreads();
  if (tid < 64) {
    float su = red[0][tid] + red[1][tid] + red[2][tid] + red[3][tid];
    float sqq = red[4][tid] + red[5][tid] + red[6][tid] + red[7][tid];
    float m = su * (1.f / Cz);
    float var = sqq * (1.f / Cz) - m * m;
    ms[tid] = m;
    rs[tid] = rsqrtf(var + 1e-5f);
  }
  __syncthreads();
  float m = ms[tl], rr = rs[tl];
  for (int c = grp; c < Cz; c += 4) {
    float v = x[bx + (size_t)c * TS] + y[by + (size_t)c * Tz];
    x[bx + (size_t)c * TS] = (v - m) * rr * g[c] + bb[c];
  }
}

// ---------------------------------------------------------------------------
extern "C" void kernel_launch(void* const* d_in, const int* in_sizes, int n_in,
                              void* d_out, int out_size, void* d_ws,
                              size_t ws_size, hipStream_t stream) {
  const float* x = (const float*)d_in[0];
  const float* xm = (const float*)d_in[1];
  const float* wq = (const float*)d_in[2];
  const float* bq = (const float*)d_in[3];
  const float* wk = (const float*)d_in[4];
  const float* bk = (const float*)d_in[5];
  const float* wv = (const float*)d_in[6];
  const float* bv = (const float*)d_in[7];
  const float* wo = (const float*)d_in[8];
  const float* bo = (const float*)d_in[9];
  const float* erk = (const float*)d_in[10];
  const float* erv = (const float*)d_in[11];
  const float* g1 = (const float*)d_in[12];
  const float* b1 = (const float*)d_in[13];
  const float* fw1 = (const float*)d_in[14];
  const float* fb1 = (const float*)d_in[15];
  const float* fw2 = (const float*)d_in[16];
  const float* fb2 = (const float*)d_in[17];
  const float* g2 = (const float*)d_in[18];
  const float* b2 = (const float*)d_in[19];

  const size_t NBC = (size_t)Bz * Cz * Tz;      // 1,048,576
  const size_t XBN = (size_t)Bz * Cz * TS;      // 1,056,768
  const size_t HP = (size_t)Bz * PROWS * FCz;   // 4,202,496 u16/array
  const size_t XP = (size_t)Bz * PROWS * Cz;    // 1,050,624 u16/array
  const size_t WPC = (size_t)3 * 1024 * 256;    // 786,432 u16/array
  const size_t QS = (size_t)Bz * Hz * Tz * KCz; // 1,048,576 u16/array

  float* ws = (float*)d_ws;
  float* xb = ws;             // padded fp32 activation
  float* yb = xb + XBN;       // fp32 residual branch
  float* unf = yb + NBC;      // union: packed q/k/v  OR  packed FFN hidden
  u16* hpH = (u16*)unf;
  u16* hpL = hpH + HP;
  u16* Qh = (u16*)unf;
  u16* Ql = Qh + QS;
  u16* Kh = Ql + QS;
  u16* Kl = Kh + QS;
  u16* Vh = Kl + QS;
  u16* Vl = Vh + QS;
  float* xpf = unf + HP;      // HP floats == 2*HP u16
  u16* xpH = (u16*)xpf;
  u16* xpL = xpH + XP;
  float* wpf = xpf + XP;      // XP floats == 2*XP u16
  u16* wpH = (u16*)wpf;
  u16* wpL = wpH + WPC;
  float* pbias = wpf + WPC;   // WPC floats == 2*WPC u16
  float* erf = pbias + 1024;
  u16* ekH = (u16*)erf;
  u16* ekL = ekH + 2048;
  u16* evH = ekL + 2048;
  u16* evL = evH + 2048;

  const int ntot = (int)NBC;
  mask_in<<<dim3((ntot + 255) / 256), 256, 0, stream>>>(x, xm, xb);
  zero_halo<<<dim3((Bz * 2 * Cz + 255) / 256), 256, 0, stream>>>(xpH, xpL, Cz);
  tpack<<<dim3(16, 4, 4), 256, 0, stream>>>(xb, TS, PADF, xm, 1, xpH, xpL, Cz);

  for (int l = 0; l < Lz; l++) {
    pack_qkvwo<<<dim3(1024, 1, 1), 256, 0, stream>>>(
        wq + (size_t)l * Cz * Cz, wk + (size_t)l * Cz * Cz,
        wv + (size_t)l * Cz * Cz, wo + (size_t)l * Cz * Cz, bq + l * Cz,
        bk + l * Cz, bv + l * Cz, bo + l * Cz, wpH, wpL, pbias);
    pack_er<<<dim3(16, 1, 1), 256, 0, stream>>>(
        erk + (size_t)l * NR * KCz, erv + (size_t)l * NR * KCz, ekH, ekL, evH,
        evL);
    mfma_gemm<1, 0><<<dim3(16, 12, 4), 256, 0, stream>>>(
        wpH, wpL, xpH, xpL, pbias, xm, nullptr, 0, 0, nullptr, nullptr, Qh, Ql,
        Kh, Kl, Vh, Vl, 1024, Cz, 0);
    attn_mfma<<<dim3(16, 16), 256, 0, stream>>>(Qh, Ql, Kh, Kl, Vh, Vl, xm,
                                                ekH, ekL, evH, evL, xpH, xpL);
    mfma_gemm<1, 1><<<dim3(16, 4, 4), 256, 0, stream>>>(
        wpH, wpL, xpH, xpL, pbias, xm, yb, 768, 0, nullptr, nullptr, nullptr,
        nullptr, nullptr, nullptr, nullptr, nullptr, 1024, Cz, 768);
    add_ln<<<dim3(16, 4), 256, 0, stream>>>(xb, yb, g1 + l * Cz, b1 + l * Cz);
    tpack<<<dim3(16, 4, 4), 256, 0, stream>>>(xb, TS, PADF, xm, 1, xpH, xpL,
                                              Cz);
    zero_halo<<<dim3((Bz * 2 * FCz + 255) / 256), 256, 0, stream>>>(hpH, hpL,
                                                                    FCz);
    pack_w3<<<dim3((3 * FCz * Cz + 255) / 256), 256, 0, stream>>>(
        fw1 + (size_t)l * FCz * Cz * 3, wpH, wpL, FCz, Cz);
    mfma_gemm<3, 2><<<dim3(16, 16, 4), 256, 0, stream>>>(
        wpH, wpL, xpH, xpL, fb1 + l * FCz, xm, nullptr, 0, 0, hpH, hpL,
        nullptr, nullptr, nullptr, nullptr, nullptr, nullptr, FCz, Cz, 0);
    pack_w3<<<dim3((3 * Cz * FCz + 255) / 256), 256, 0, stream>>>(
        fw2 + (size_t)l * Cz * FCz * 3, wpH, wpL, Cz, FCz);
    mfma_gemm<3, 1><<<dim3(16, 4, 4), 256, 0, stream>>>(
        wpH, wpL, hpH, hpL, fb2 + l * Cz, xm, yb, 0, 1, nullptr, nullptr,
        nullptr, nullptr, nullptr, nullptr, nullptr, nullptr, Cz, FCz, 0);
    add_ln<<<dim3(16, 4), 256, 0, stream>>>(xb, yb, g2 + l * Cz, b2 + l * Cz);
    tpack<<<dim3(16, 4, 4), 256, 0, stream>>>(xb, TS, PADF, xm, 1, xpH, xpL,
                                              Cz);
  }
  mask_out<<<dim3((ntot + 255) / 256), 256, 0, stream>>>(xb, xm,
                                                         (float*)d_out);
}

// Round 6
// 1274.710 us; speedup vs baseline: 4.3869x; 1.2729x over previous
//
#include <hip/hip_runtime.h>

// Encoder: L=6 layers of (rel-pos attention + channel-LN + K=3 conv FFN + LN)
// B=4, C=256, T=1024, H=4, KC=64, FC=1024, W=10, fp32 I/O.
// All heavy math via split-bf16 (hi/lo) emulated-fp32 MFMA
// (3 passes of mfma_f32_16x16x32_bf16), including attention.

#define Lz 6
#define Cz 256
#define FCz 1024
#define Hz 4
#define Wz 10
#define Bz 4
#define Tz 1024
#define KCz 64
#define NR 21
#define TS 1032  // padded fp32 activation row stride
#define PADF 4
#define PROWS 1026  // packed channel-last rows: 1 halo + 1024 + 1 halo

typedef unsigned short u16;
typedef unsigned int u32;
typedef __attribute__((ext_vector_type(8))) short bf8v;   // 8 bf16 = 4 VGPR
typedef __attribute__((ext_vector_type(4))) float f4v;

#define MFMA(a, b, c) __builtin_amdgcn_mfma_f32_16x16x32_bf16(a, b, c, 0, 0, 0)

__device__ inline void bf_split(float v, u16& hi, u16& lo) {
  unsigned u = __float_as_uint(v);
  unsigned hr = (u + 0x7FFFu + ((u >> 16) & 1u)) >> 16;
  float rem = v - __uint_as_float(hr << 16);
  unsigned u2 = __float_as_uint(rem);
  unsigned lr = (u2 + 0x7FFFu + ((u2 >> 16) & 1u)) >> 16;
  hi = (u16)hr;
  lo = (u16)lr;
}

// ---------------------------------------------------------------------------
__global__ __launch_bounds__(256) void mask_in(const float* __restrict__ x,
                                               const float* __restrict__ m,
                                               float* __restrict__ xp) {
  int id = blockIdx.x * 256 + threadIdx.x;
  if (id < Bz * Cz * Tz) {
    int t = id & (Tz - 1), row = id >> 10, b = id >> 18;
    xp[(size_t)row * TS + PADF + t] = x[id] * m[b * Tz + t];
  }
}

__global__ __launch_bounds__(256) void mask_out(const float* __restrict__ xp,
                                                const float* __restrict__ m,
                                                float* __restrict__ out) {
  int id = blockIdx.x * 256 + threadIdx.x;
  if (id < Bz * Cz * Tz) {
    int t = id & (Tz - 1), row = id >> 10, b = id >> 18;
    out[id] = xp[(size_t)row * TS + PADF + t] * m[b * Tz + t];
  }
}

// zero halo rows (0 and 1025) of packed [B][1026][Cd] hi/lo pair
__global__ __launch_bounds__(256) void zero_halo(u16* hi, u16* lo, int Cd) {
  int id = blockIdx.x * 256 + threadIdx.x;
  if (id >= Bz * 2 * Cd) return;
  int c = id % Cd, rb = id / Cd, b = rb >> 1, s = rb & 1;
  size_t a = ((size_t)b * PROWS + (s ? (PROWS - 1) : 0)) * Cd + c;
  hi[a] = 0;
  lo[a] = 0;
}

// ---------------------------------------------------------------------------
// Transpose-pack (initial x' only): fp32 [b][Cd][TS] -> hi/lo [b][1026][Cd]
// ---------------------------------------------------------------------------
__global__ __launch_bounds__(256) void tpack(const float* __restrict__ src,
                                             const float* __restrict__ mask,
                                             u16* __restrict__ dhi,
                                             u16* __restrict__ dlo, int Cd) {
  __shared__ float L[64 * 68];
  const int tid = threadIdx.x;
  const int t0 = blockIdx.x * 64, c0 = blockIdx.y * 64, b = blockIdx.z;
  const float* sb = src + (size_t)b * Cd * TS + PADF;
#pragma unroll
  for (int i = 0; i < 16; i++) {
    int id = tid + 256 * i;
    int cc = id >> 6, tt = id & 63;
    L[cc * 68 + tt] = sb[(size_t)(c0 + cc) * TS + t0 + tt];
  }
  __syncthreads();
  const int tt = tid >> 2, p = tid & 3;
  float mv = mask[(size_t)b * Tz + t0 + tt];
  u16 hs[16], ls[16];
#pragma unroll
  for (int j = 0; j < 16; j++) {
    float v = L[(p * 16 + j) * 68 + tt] * mv;
    bf_split(v, hs[j], ls[j]);
  }
  size_t da = ((size_t)b * PROWS + t0 + tt + 1) * Cd + c0 + p * 16;
  *(uint4*)&dhi[da] = *(uint4*)&hs[0];
  *(uint4*)&dhi[da + 8] = *(uint4*)&hs[8];
  *(uint4*)&dlo[da] = *(uint4*)&ls[0];
  *(uint4*)&dlo[da + 8] = *(uint4*)&ls[8];
}

// ---------------------------------------------------------------------------
// One-launch per-layer weight packing: qkvwo + er + conv1 w + conv2 w.
// grid 7184 blocks: [0,1024) qkvwo, [1024,1040) er, [1040,4112) w1, rest w2.
// ---------------------------------------------------------------------------
__global__ __launch_bounds__(256) void pack_all(
    const float* __restrict__ wq, const float* __restrict__ wk,
    const float* __restrict__ wv, const float* __restrict__ wo_,
    const float* __restrict__ bq, const float* __restrict__ bk,
    const float* __restrict__ bv, const float* __restrict__ bo,
    const float* __restrict__ erk, const float* __restrict__ erv,
    const float* __restrict__ fw1, const float* __restrict__ fw2,
    u16* __restrict__ qwH, u16* __restrict__ qwL, float* __restrict__ pb,
    u16* __restrict__ ekH, u16* __restrict__ ekL, u16* __restrict__ evH,
    u16* __restrict__ evL, u16* __restrict__ w1H, u16* __restrict__ w1L,
    u16* __restrict__ w2H, u16* __restrict__ w2L) {
  const int blk = blockIdx.x, tid = threadIdx.x;
  if (blk < 1024) {
    int id = blk * 256 + tid;
    int o = id >> 8, c = id & 255;
    int sel = o >> 8;
    const float* w = sel == 0 ? wq : (sel == 1 ? wk : (sel == 2 ? wv : wo_));
    float v = w[((size_t)(o & 255) << 8) + c];
    bf_split(v, qwH[id], qwL[id]);
    if (id < 1024) {
      int s2 = id >> 8;
      const float* bs = s2 == 0 ? bq : (s2 == 1 ? bk : (s2 == 2 ? bv : bo));
      pb[id] = bs[id & 255];
    }
  } else if (blk < 1040) {
    int id = (blk - 1024) * 256 + tid;
    if (id < 2048) {
      int rr = id >> 6, d = id & 63;
      float v = (rr < NR) ? erk[rr * KCz + d] : 0.f;
      bf_split(v, ekH[id], ekL[id]);
    } else {
      int id2 = id - 2048;
      int d = id2 >> 5, rr = id2 & 31;
      float v = (rr < NR) ? erv[rr * KCz + d] : 0.f;
      bf_split(v, evH[id2], evL[id2]);
    }
  } else if (blk < 4112) {
    int id = (blk - 1040) * 256 + tid;
    int c = id % Cz;
    int rest = id / Cz;
    int o = rest % FCz, tap = rest / FCz;
    float v = fw1[((size_t)o * Cz + c) * 3 + tap];
    bf_split(v, w1H[id], w1L[id]);
  } else {
    int id = (blk - 4112) * 256 + tid;
    int c = id % FCz;
    int rest = id / FCz;
    int o = rest % Cz, tap = rest / Cz;
    float v = fw2[((size_t)o * FCz + c) * 3 + tap];
    bf_split(v, w2H[id], w2L[id]);
  }
}

// ---------------------------------------------------------------------------
// Split-bf16 MFMA GEMM: D[m][t] = sum_{tap,c} A[tap][m][c] * Bp[t+tap][c]
// Block tile 64m x 64t, 4 waves of 32x32, K-tile 32; 3 mfma passes per tile.
// EPI 0: qkv -> packed Q(x0.125)/K [b][h][t][d], V [b][h][d][t].
// EPI 1: out fp32 [b][256][Tz] rows (m - m_base), +bias, optional mask.
// EPI 2: +bias, relu, mask, split -> packed [B][1026][M] rows +1 (conv1).
// EPI 3: K-split halves (blockIdx.y = mtile*2+khalf) -> raw fp32 partials.
// ---------------------------------------------------------------------------
template <int TAPS, int EPI>
__global__ __launch_bounds__(256) void mfma_gemm(
    const u16* __restrict__ Ah, const u16* __restrict__ Al,
    const u16* __restrict__ Bh, const u16* __restrict__ Bl,
    const float* __restrict__ bias, const float* __restrict__ mask,
    float* __restrict__ out, float* __restrict__ out2, int amask,
    u16* __restrict__ ph, u16* __restrict__ pl, u16* __restrict__ pqh,
    u16* __restrict__ pql, u16* __restrict__ pkh, u16* __restrict__ pkl,
    u16* __restrict__ pvh, u16* __restrict__ pvl, int M, int Kc, int m_base) {
  __shared__ u16 sm[4 * 64 * 40];  // Ash, Asl, Bsh, Bsl
  u16* Ash = sm;
  u16* Asl = sm + 2560;
  u16* Bsh = sm + 5120;
  u16* Bsl = sm + 7680;
  const int tid = threadIdx.x;
  const int lane = tid & 63, wid = tid >> 6;
  const int wm = wid & 1, wn = wid >> 1;
  const int r = lane & 15, qd = lane >> 4;
  const int t0 = blockIdx.x * 64;
  const int b = blockIdx.z;
  const int srow = tid >> 2, sseg = (tid & 3) * 8;

  int m0, kc0, kcN;
  float* outp = out;
  if constexpr (EPI == 3) {
    m0 = (blockIdx.y >> 1) * 64;
    kc0 = (blockIdx.y & 1) * (Kc / 2);
    kcN = Kc / 2;
    outp = (blockIdx.y & 1) ? out2 : out;
  } else {
    m0 = blockIdx.y * 64 + m_base;
    kc0 = 0;
    kcN = Kc;
  }

  f4v acc[2][2];
#pragma unroll
  for (int i = 0; i < 2; i++)
#pragma unroll
    for (int j = 0; j < 2; j++) acc[i][j] = (f4v)(0.f);

  for (int tap = 0; tap < TAPS; tap++) {
    const u16* Ath = Ah + (size_t)tap * M * Kc;
    const u16* Atl = Al + (size_t)tap * M * Kc;
    const int tofs = (TAPS == 1) ? 1 : tap;
    const size_t arow = (size_t)(m0 + srow) * Kc + kc0;
    const size_t brow = ((size_t)b * PROWS + t0 + tofs + srow) * Kc + kc0;
    for (int kc = 0; kc < kcN; kc += 32) {
      *(uint4*)&Ash[srow * 40 + sseg] = *(const uint4*)&Ath[arow + kc + sseg];
      *(uint4*)&Asl[srow * 40 + sseg] = *(const uint4*)&Atl[arow + kc + sseg];
      *(uint4*)&Bsh[srow * 40 + sseg] = *(const uint4*)&Bh[brow + kc + sseg];
      *(uint4*)&Bsl[srow * 40 + sseg] = *(const uint4*)&Bl[brow + kc + sseg];
      __syncthreads();
      bf8v ah[2], al[2], bh[2], bl[2];
#pragma unroll
      for (int f = 0; f < 2; f++) {
        int ar = (wm * 32 + f * 16 + r) * 40 + qd * 8;
        int br = (wn * 32 + f * 16 + r) * 40 + qd * 8;
        ah[f] = *(bf8v*)&Ash[ar];
        al[f] = *(bf8v*)&Asl[ar];
        bh[f] = *(bf8v*)&Bsh[br];
        bl[f] = *(bf8v*)&Bsl[br];
      }
#pragma unroll
      for (int mf = 0; mf < 2; mf++)
#pragma unroll
        for (int nf = 0; nf < 2; nf++) {
          acc[mf][nf] = MFMA(ah[mf], bh[nf], acc[mf][nf]);
          acc[mf][nf] = MFMA(al[mf], bh[nf], acc[mf][nf]);
          acc[mf][nf] = MFMA(ah[mf], bl[nf], acc[mf][nf]);
        }
      __syncthreads();
    }
  }

  float* Ds = (float*)sm;  // 64x68 fp32 staging
  if constexpr (EPI == 0) {
    const int sel = m0 >> 8;  // 0 q, 1 k, 2 v
    const int h = (m0 >> 6) & 3;
    const int bhI = b * Hz + h;
    if (sel < 2) {
#pragma unroll
      for (int mf = 0; mf < 2; mf++)
#pragma unroll
        for (int nf = 0; nf < 2; nf++) {
          int nl = wn * 32 + nf * 16 + r;
          int ml = wm * 32 + mf * 16 + qd * 4;
          *(f4v*)&Ds[nl * 68 + ml] = acc[mf][nf];
        }
      __syncthreads();
      const int row = tid >> 2, p = tid & 3;
      const float scq = (sel == 0) ? 0.125f : 1.f;
      u16 hs[16], ls[16];
#pragma unroll
      for (int jj = 0; jj < 4; jj++) {
        float4 dv = *(float4*)&Ds[row * 68 + p * 16 + jj * 4];
        float4 bb = *(const float4*)&bias[m0 + p * 16 + jj * 4];
        float vv[4] = {(dv.x + bb.x) * scq, (dv.y + bb.y) * scq,
                       (dv.z + bb.z) * scq, (dv.w + bb.w) * scq};
#pragma unroll
        for (int e = 0; e < 4; e++)
          bf_split(vv[e], hs[jj * 4 + e], ls[jj * 4 + e]);
      }
      u16* oh = (sel == 0) ? pqh : pkh;
      u16* ol = (sel == 0) ? pql : pkl;
      size_t da = ((size_t)bhI * Tz + t0 + row) * KCz + p * 16;
      *(uint4*)&oh[da] = *(uint4*)&hs[0];
      *(uint4*)&oh[da + 8] = *(uint4*)&hs[8];
      *(uint4*)&ol[da] = *(uint4*)&ls[0];
      *(uint4*)&ol[da + 8] = *(uint4*)&ls[8];
    } else {
#pragma unroll
      for (int mf = 0; mf < 2; mf++)
#pragma unroll
        for (int nf = 0; nf < 2; nf++) {
          int ml = wm * 32 + mf * 16 + qd * 4;
          int nl = wn * 32 + nf * 16 + r;
#pragma unroll
          for (int e = 0; e < 4; e++) Ds[(ml + e) * 68 + nl] = acc[mf][nf][e];
        }
      __syncthreads();
      const int row = tid >> 2, p = tid & 3;
      const float bb = bias[m0 + row];
      u16 hs[16], ls[16];
#pragma unroll
      for (int jj = 0; jj < 16; jj++)
        bf_split(Ds[row * 68 + p * 16 + jj] + bb, hs[jj], ls[jj]);
      size_t da = ((size_t)bhI * KCz + row) * Tz + t0 + p * 16;
      *(uint4*)&pvh[da] = *(uint4*)&hs[0];
      *(uint4*)&pvh[da + 8] = *(uint4*)&hs[8];
      *(uint4*)&pvl[da] = *(uint4*)&ls[0];
      *(uint4*)&pvl[da + 8] = *(uint4*)&ls[8];
    }
  } else if constexpr (EPI == 2) {
#pragma unroll
    for (int mf = 0; mf < 2; mf++)
#pragma unroll
      for (int nf = 0; nf < 2; nf++) {
        int nl = wn * 32 + nf * 16 + r;
        int ml = wm * 32 + mf * 16 + qd * 4;
        *(f4v*)&Ds[nl * 68 + ml] = acc[mf][nf];
      }
    __syncthreads();
    const int row = tid >> 2, p = tid & 3;
    const int t = t0 + row;
    float mv = mask[(size_t)b * Tz + t];
    u16 hs[16], ls[16];
#pragma unroll
    for (int jj = 0; jj < 4; jj++) {
      float4 dv = *(float4*)&Ds[row * 68 + p * 16 + jj * 4];
      float4 bb = *(const float4*)&bias[m0 + p * 16 + jj * 4];
      float vv[4] = {dv.x + bb.x, dv.y + bb.y, dv.z + bb.z, dv.w + bb.w};
#pragma unroll
      for (int e = 0; e < 4; e++) {
        float v = fmaxf(vv[e], 0.f) * mv;
        bf_split(v, hs[jj * 4 + e], ls[jj * 4 + e]);
      }
    }
    size_t da = ((size_t)b * PROWS + t + 1) * M + m0 + p * 16;
    *(uint4*)&ph[da] = *(uint4*)&hs[0];
    *(uint4*)&ph[da + 8] = *(uint4*)&hs[8];
    *(uint4*)&pl[da] = *(uint4*)&ls[0];
    *(uint4*)&pl[da + 8] = *(uint4*)&ls[8];
  } else {
    // EPI 1 / EPI 3: Ds[m][n] -> fp32 rows
#pragma unroll
    for (int mf = 0; mf < 2; mf++)
#pragma unroll
      for (int nf = 0; nf < 2; nf++) {
        int ml = wm * 32 + mf * 16 + qd * 4;
        int nl = wn * 32 + nf * 16 + r;
#pragma unroll
        for (int e = 0; e < 4; e++) Ds[(ml + e) * 68 + nl] = acc[mf][nf][e];
      }
    __syncthreads();
    const int row = tid >> 2, p = tid & 3;
    if constexpr (EPI == 3) {
      size_t oa = ((size_t)b * Cz + m0 + row) * Tz + t0 + p * 16;
#pragma unroll
      for (int jj = 0; jj < 4; jj++)
        *(float4*)&outp[oa + jj * 4] = *(float4*)&Ds[row * 68 + p * 16 + jj * 4];
    } else {
      const int m = m0 + row;
      const float bb = bias[m];
      size_t oa = ((size_t)b * Cz + (m - m_base)) * Tz + t0 + p * 16;
#pragma unroll
      for (int jj = 0; jj < 4; jj++) {
        float4 dv = *(float4*)&Ds[row * 68 + p * 16 + jj * 4];
        float4 rv = make_float4(dv.x + bb, dv.y + bb, dv.z + bb, dv.w + bb);
        if (amask) {
          float4 mk =
              *(const float4*)&mask[(size_t)b * Tz + t0 + p * 16 + jj * 4];
          rv.x *= mk.x; rv.y *= mk.y; rv.z *= mk.z; rv.w *= mk.w;
        }
        *(float4*)&outp[oa + jj * 4] = rv;
      }
    }
  }
}

// ---------------------------------------------------------------------------
// MFMA flash attention, 32 q-rows per block, 2 waves (128 thr), grid (32,B*H).
// Inputs packed hi/lo: Q(x0.125)/K [b][h][t][d]; V [b][h][d][t]. Output packed
// hi/lo [B][1026][256] rows+1 (wo-GEMM B layout).
// ---------------------------------------------------------------------------
__global__ __launch_bounds__(128) void attn_mfma(
    const u16* __restrict__ Qh_, const u16* __restrict__ Ql_,
    const u16* __restrict__ Kh_, const u16* __restrict__ Kl_,
    const u16* __restrict__ Vh_, const u16* __restrict__ Vl_,
    const float* __restrict__ mask, const u16* __restrict__ erkH,
    const u16* __restrict__ erkL, const u16* __restrict__ ervH,
    const u16* __restrict__ ervL, u16* __restrict__ outH,
    u16* __restrict__ outL) {
  __shared__ __align__(16) char smraw[50816];
  u16* Ksh = (u16*)smraw;                   // [64][72]
  u16* Ksl = (u16*)(smraw + 9216);
  u16* Vsh = (u16*)(smraw + 18432);         // [64][72] (V^T: [d][j])
  u16* Vsl = (u16*)(smraw + 27648);         // end 36864
  u32* Psp = (u32*)(smraw + 36864);         // [32][66] packed P -> 8448 B
  float* rqs = (float*)(smraw + 45312);     // [32][21]
  float* bands = (float*)(smraw + 48000);   // [32][21]
  float* mrowS = (float*)(smraw + 50688);   // [32]

  const int tid = threadIdx.x;
  const int lane = tid & 63, wid = tid >> 6;  // wid 0/1
  const int r = lane & 15, qd = lane >> 4;
  const int iw = wid * 16;
  const int i0 = blockIdx.x * 32;
  const int bh = blockIdx.y;
  const int b = bh >> 2, h = bh & 3;
  const float* mb = mask + (size_t)b * Tz;
  const size_t qkbase = (size_t)bh * Tz * KCz;
  const size_t vbase = (size_t)bh * KCz * Tz;

  bf8v qh[2], ql[2];
  {
    const size_t qrow = qkbase + (size_t)(i0 + iw + r) * KCz;
#pragma unroll
    for (int ks = 0; ks < 2; ks++) {
      qh[ks] = *(const bf8v*)&Qh_[qrow + ks * 32 + qd * 8];
      ql[ks] = *(const bf8v*)&Ql_[qrow + ks * 32 + qd * 8];
    }
  }
  for (int id = tid; id < 32 * NR; id += 128) bands[id] = -1e30f;

  // rq[i][rr] = q^ . erk via MFMA (16 wave-local rows)
  {
    f4v rc[2] = {(f4v)(0.f), (f4v)(0.f)};
#pragma unroll
    for (int nf = 0; nf < 2; nf++)
#pragma unroll
      for (int ks = 0; ks < 2; ks++) {
        bf8v eh = *(const bf8v*)&erkH[(16 * nf + r) * 64 + ks * 32 + qd * 8];
        bf8v el = *(const bf8v*)&erkL[(16 * nf + r) * 64 + ks * 32 + qd * 8];
        rc[nf] = MFMA(qh[ks], eh, rc[nf]);
        rc[nf] = MFMA(ql[ks], eh, rc[nf]);
        rc[nf] = MFMA(qh[ks], el, rc[nf]);
      }
#pragma unroll
    for (int nf = 0; nf < 2; nf++) {
      int rr = 16 * nf + r;
      if (rr < NR) {
#pragma unroll
        for (int e = 0; e < 4; e++)
          rqs[(iw + 4 * qd + e) * NR + rr] = rc[nf][e];
      }
    }
  }

  float qm4[4];
#pragma unroll
  for (int e = 0; e < 4; e++) qm4[e] = mb[i0 + iw + 4 * qd + e];

  float m_st[4] = {-1e30f, -1e30f, -1e30f, -1e30f};
  float l_st[4] = {0.f, 0.f, 0.f, 0.f};
  f4v oacc[4];
#pragma unroll
  for (int nf = 0; nf < 4; nf++) oacc[nf] = (f4v)(0.f);
  __syncthreads();

  for (int j0t = 0; j0t < 16; j0t++) {
    const int j0 = j0t * 64;
    __syncthreads();  // prev tile's K/V reads complete
    {
      const int row = tid >> 1, seg = (tid & 1) * 32;
      const size_t krow = qkbase + (size_t)(j0 + row) * KCz + seg;
      const size_t vrow = vbase + (size_t)row * Tz + j0 + seg;
#pragma unroll
      for (int o8 = 0; o8 < 32; o8 += 8) {
        *(uint4*)&Ksh[row * 72 + seg + o8] = *(const uint4*)&Kh_[krow + o8];
        *(uint4*)&Ksl[row * 72 + seg + o8] = *(const uint4*)&Kl_[krow + o8];
        *(uint4*)&Vsh[row * 72 + seg + o8] = *(const uint4*)&Vh_[vrow + o8];
        *(uint4*)&Vsl[row * 72 + seg + o8] = *(const uint4*)&Vl_[vrow + o8];
      }
    }
    __syncthreads();

    // S = q^ K^T (3-pass)
    f4v sa[4];
#pragma unroll
    for (int nf = 0; nf < 4; nf++) sa[nf] = (f4v)(0.f);
#pragma unroll
    for (int nf = 0; nf < 4; nf++)
#pragma unroll
      for (int ks = 0; ks < 2; ks++) {
        bf8v kh = *(bf8v*)&Ksh[(16 * nf + r) * 72 + ks * 32 + qd * 8];
        bf8v kl = *(bf8v*)&Ksl[(16 * nf + r) * 72 + ks * 32 + qd * 8];
        sa[nf] = MFMA(qh[ks], kh, sa[nf]);
        sa[nf] = MFMA(ql[ks], kh, sa[nf]);
        sa[nf] = MFMA(qh[ks], kl, sa[nf]);
      }

    float km4[4];
#pragma unroll
    for (int nf = 0; nf < 4; nf++) km4[nf] = mb[j0 + 16 * nf + r];
    float rmax[4] = {-1e30f, -1e30f, -1e30f, -1e30f};
    float sv[4][4];
#pragma unroll
    for (int nf = 0; nf < 4; nf++)
#pragma unroll
      for (int e = 0; e < 4; e++) {
        int ii = iw + 4 * qd + e;
        int dl = (j0 + 16 * nf + r) - (i0 + ii);
        float s = sa[nf][e];
        bool inb = (unsigned)(dl + Wz) <= 2u * Wz;
        if (inb) s += rqs[ii * NR + dl + Wz];
        if (qm4[e] * km4[nf] == 0.f) s = -1e4f;
        if (inb) bands[ii * NR + dl + Wz] = s;
        sv[nf][e] = s;
        rmax[e] = fmaxf(rmax[e], s);
      }
#pragma unroll
    for (int off = 1; off < 16; off <<= 1)
#pragma unroll
      for (int e = 0; e < 4; e++)
        rmax[e] = fmaxf(rmax[e], __shfl_xor(rmax[e], off, 16));

    float al[4], psum[4];
#pragma unroll
    for (int e = 0; e < 4; e++) {
      float mn = fmaxf(m_st[e], rmax[e]);
      al[e] = __expf(m_st[e] - mn);
      m_st[e] = mn;
      l_st[e] *= al[e];
      psum[e] = 0.f;
    }
#pragma unroll
    for (int nf = 0; nf < 4; nf++)
#pragma unroll
      for (int e = 0; e < 4; e++) {
        float p = __expf(sv[nf][e] - m_st[e]);
        psum[e] += p;
        u16 hi, lo;
        bf_split(p, hi, lo);
        Psp[(iw + 4 * qd + e) * 66 + 16 * nf + r] = (u32)hi | ((u32)lo << 16);
      }
#pragma unroll
    for (int off = 1; off < 16; off <<= 1)
#pragma unroll
      for (int e = 0; e < 4; e++) psum[e] += __shfl_xor(psum[e], off, 16);
#pragma unroll
    for (int e = 0; e < 4; e++) l_st[e] += psum[e];
#pragma unroll
    for (int nf = 0; nf < 4; nf++)
#pragma unroll
      for (int e = 0; e < 4; e++) oacc[nf][e] *= al[e];

    // O += P V (wave-local P rows; no barrier)
#pragma unroll
    for (int ks = 0; ks < 2; ks++) {
      u32 w8[8];
      const u32* pp = &Psp[(iw + r) * 66 + ks * 32 + qd * 8];
#pragma unroll
      for (int k2 = 0; k2 < 4; k2++) {
        uint2 t2 = *(uint2*)&pp[2 * k2];
        w8[2 * k2] = t2.x;
        w8[2 * k2 + 1] = t2.y;
      }
      union { bf8v v; u32 u[4]; } Ph, Pl;
#pragma unroll
      for (int k2 = 0; k2 < 4; k2++) {
        Ph.u[k2] = (w8[2 * k2] & 0xffffu) | (w8[2 * k2 + 1] << 16);
        Pl.u[k2] = (w8[2 * k2] >> 16) | (w8[2 * k2 + 1] & 0xffff0000u);
      }
#pragma unroll
      for (int nf = 0; nf < 4; nf++) {
        bf8v vh = *(bf8v*)&Vsh[(16 * nf + r) * 72 + ks * 32 + qd * 8];
        bf8v vl = *(bf8v*)&Vsl[(16 * nf + r) * 72 + ks * 32 + qd * 8];
        oacc[nf] = MFMA(Ph.v, vh, oacc[nf]);
        oacc[nf] = MFMA(Pl.v, vh, oacc[nf]);
        oacc[nf] = MFMA(Ph.v, vl, oacc[nf]);
      }
    }
  }

  if (r == 0) {
#pragma unroll
    for (int e = 0; e < 4; e++) mrowS[iw + 4 * qd + e] = m_st[e];
  }
  __syncthreads();

  // band probs -> packed bf16 [32][36] (reusing Psp region)
  u32* bandsP = Psp;
  for (int id = tid; id < 32 * 32; id += 128) {
    int i = id >> 5, rr = id & 31;
    float p = (rr < NR) ? __expf(bands[i * NR + rr] - mrowS[i]) : 0.f;
    u16 hi, lo;
    bf_split(p, hi, lo);
    bandsP[i * 36 + rr] = (u32)hi | ((u32)lo << 16);
  }
  __syncthreads();

  // O += bandP . erv via MFMA
  {
    u32 w8[8];
    const u32* pp = &bandsP[(iw + r) * 36 + qd * 8];
#pragma unroll
    for (int k2 = 0; k2 < 2; k2++) {
      uint4 t4 = *(uint4*)&pp[4 * k2];
      w8[4 * k2] = t4.x; w8[4 * k2 + 1] = t4.y;
      w8[4 * k2 + 2] = t4.z; w8[4 * k2 + 3] = t4.w;
    }
    union { bf8v v; u32 u[4]; } Ph, Pl;
#pragma unroll
    for (int k2 = 0; k2 < 4; k2++) {
      Ph.u[k2] = (w8[2 * k2] & 0xffffu) | (w8[2 * k2 + 1] << 16);
      Pl.u[k2] = (w8[2 * k2] >> 16) | (w8[2 * k2 + 1] & 0xffff0000u);
    }
#pragma unroll
    for (int nf = 0; nf < 4; nf++) {
      bf8v eh = *(const bf8v*)&ervH[(16 * nf + r) * 32 + qd * 8];
      bf8v el = *(const bf8v*)&ervL[(16 * nf + r) * 32 + qd * 8];
      oacc[nf] = MFMA(Ph.v, eh, oacc[nf]);
      oacc[nf] = MFMA(Pl.v, eh, oacc[nf]);
      oacc[nf] = MFMA(Ph.v, el, oacc[nf]);
    }
  }

  // normalize, stage O[i][d], pack out
  float* Os = (float*)smraw;  // [32][68]
  float linv[4];
#pragma unroll
  for (int e = 0; e < 4; e++) linv[e] = 1.f / l_st[e];
#pragma unroll
  for (int nf = 0; nf < 4; nf++)
#pragma unroll
    for (int e = 0; e < 4; e++)
      Os[(iw + 4 * qd + e) * 68 + 16 * nf + r] = oacc[nf][e] * linv[e];
  __syncthreads();
  {
    const int row = tid >> 2, p = tid & 3;
    const float* src = &Os[row * 68 + p * 16];
    u16 hs[16], ls[16];
#pragma unroll
    for (int j = 0; j < 16; j++) bf_split(src[j], hs[j], ls[j]);
    size_t da = ((size_t)b * PROWS + i0 + row + 1) * Cz + h * 64 + p * 16;
    *(uint4*)&outH[da] = *(uint4*)&hs[0];
    *(uint4*)&outH[da + 8] = *(uint4*)&hs[8];
    *(uint4*)&outL[da] = *(uint4*)&ls[0];
    *(uint4*)&outL[da + 8] = *(uint4*)&ls[8];
  }
}

// ---------------------------------------------------------------------------
// Fused residual + channel LayerNorm + transpose-pack.
// VAR 0: x = LN(x + y); VAR 1: x = LN(x + (y + p1 + cbias)*mask).
// Writes xb fp32 (padded) and packed hi/lo [b][1026][256] (masked).
// grid (Tz/16, B), block 256 (16 t-lanes x 16 c-groups).
// ---------------------------------------------------------------------------
template <int VAR>
__global__ __launch_bounds__(256) void fused_ln(
    float* __restrict__ x, const float* __restrict__ y,
    const float* __restrict__ p1, const float* __restrict__ cbias,
    const float* __restrict__ g, const float* __restrict__ bb,
    const float* __restrict__ mask, u16* __restrict__ dhi,
    u16* __restrict__ dlo) {
  __shared__ float L[256 * 17];
  __shared__ float red[16][16], red2[16][16];
  __shared__ float ms[16], rs[16];
  const int tid = threadIdx.x;
  const int t0 = blockIdx.x * 16, b = blockIdx.y;
  const int tl = tid & 15, grp = tid >> 4;
  const size_t bx = (size_t)b * Cz * TS + PADF + t0 + tl;
  const size_t by = (size_t)b * Cz * Tz + t0 + tl;
  const float mv = mask[(size_t)b * Tz + t0 + tl];
  float s = 0.f, sq = 0.f;
  for (int c = grp; c < Cz; c += 16) {
    float v = x[bx + (size_t)c * TS];
    if constexpr (VAR == 0) {
      v += y[by + (size_t)c * Tz];
    } else {
      v += (y[by + (size_t)c * Tz] + p1[by + (size_t)c * Tz] + cbias[c]) * mv;
    }
    L[c * 17 + tl] = v;
    s += v;
    sq += v * v;
  }
  red[grp][tl] = s;
  red2[grp][tl] = sq;
  __syncthreads();
  if (tid < 16) {
    float su = 0.f, sqq = 0.f;
#pragma unroll
    for (int gg = 0; gg < 16; gg++) {
      su += red[gg][tid];
      sqq += red2[gg][tid];
    }
    float m = su * (1.f / Cz);
    ms[tid] = m;
    rs[tid] = rsqrtf(sqq * (1.f / Cz) - m * m + 1e-5f);
  }
  __syncthreads();
  float m = ms[tl], r = rs[tl];
  for (int c = grp; c < Cz; c += 16) {
    float v = (L[c * 17 + tl] - m) * r * g[c] + bb[c];
    x[bx + (size_t)c * TS] = v;
    L[c * 17 + tl] = v * mv;
  }
  __syncthreads();
  const int tt = tid & 15, p = tid >> 4;  // lanes along t: conflict-free LDS
  u16 hs[16], ls[16];
#pragma unroll
  for (int j = 0; j < 16; j++) bf_split(L[(p * 16 + j) * 17 + tt], hs[j], ls[j]);
  size_t da = ((size_t)b * PROWS + t0 + tt + 1) * Cz + p * 16;
  *(uint4*)&dhi[da] = *(uint4*)&hs[0];
  *(uint4*)&dhi[da + 8] = *(uint4*)&hs[8];
  *(uint4*)&dlo[da] = *(uint4*)&ls[0];
  *(uint4*)&dlo[da + 8] = *(uint4*)&ls[8];
}

// ---------------------------------------------------------------------------
extern "C" void kernel_launch(void* const* d_in, const int* in_sizes, int n_in,
                              void* d_out, int out_size, void* d_ws,
                              size_t ws_size, hipStream_t stream) {
  const float* x = (const float*)d_in[0];
  const float* xm = (const float*)d_in[1];
  const float* wq = (const float*)d_in[2];
  const float* bq = (const float*)d_in[3];
  const float* wk = (const float*)d_in[4];
  const float* bk = (const float*)d_in[5];
  const float* wv = (const float*)d_in[6];
  const float* bv = (const float*)d_in[7];
  const float* wo = (const float*)d_in[8];
  const float* bo = (const float*)d_in[9];
  const float* erk = (const float*)d_in[10];
  const float* erv = (const float*)d_in[11];
  const float* g1 = (const float*)d_in[12];
  const float* b1 = (const float*)d_in[13];
  const float* fw1 = (const float*)d_in[14];
  const float* fb1 = (const float*)d_in[15];
  const float* fw2 = (const float*)d_in[16];
  const float* fb2 = (const float*)d_in[17];
  const float* g2 = (const float*)d_in[18];
  const float* b2 = (const float*)d_in[19];

  const size_t NBC = (size_t)Bz * Cz * Tz;       // 1,048,576
  const size_t XBN = (size_t)Bz * Cz * TS;       // 1,056,768
  const size_t HP = (size_t)Bz * PROWS * FCz;    // 4,202,496 u16/array
  const size_t XP = (size_t)Bz * PROWS * Cz;     // 1,050,624 u16/array
  const size_t QS = (size_t)Bz * Hz * Tz * KCz;  // 1,048,576 u16/array

  float* ws = (float*)d_ws;
  float* xb = ws;              // padded fp32 activation
  float* yb = xb + XBN;        // fp32 residual branch / conv2 partial 0
  float* p1 = yb + NBC;        // conv2 partial 1
  float* unf = p1 + NBC;       // union: packed q/k/v OR packed FFN hidden
  u16* hpH = (u16*)unf;
  u16* hpL = hpH + HP;
  u16* Qh = (u16*)unf;
  u16* Ql = Qh + QS;
  u16* Kh = Ql + QS;
  u16* Kl = Kh + QS;
  u16* Vh = Kl + QS;
  u16* Vl = Vh + QS;
  float* xpf = unf + HP;       // HP floats == 2*HP u16
  u16* xpH = (u16*)xpf;
  u16* xpL = xpH + XP;
  float* qwf = xpf + XP;
  u16* qwH = (u16*)qwf;
  u16* qwL = qwH + 262144;
  float* w1f = qwf + 262144;
  u16* w1H = (u16*)w1f;
  u16* w1L = w1H + 786432;
  float* w2f = w1f + 786432;
  u16* w2H = (u16*)w2f;
  u16* w2L = w2H + 786432;
  float* erf = w2f + 786432;
  u16* ekH = (u16*)erf;
  u16* ekL = ekH + 2048;
  u16* evH = ekL + 2048;
  u16* evL = evH + 2048;
  float* pbias = erf + 4096;

  const int ntot = (int)NBC;
  mask_in<<<dim3((ntot + 255) / 256), 256, 0, stream>>>(x, xm, xb);
  zero_halo<<<dim3((Bz * 2 * Cz + 255) / 256), 256, 0, stream>>>(xpH, xpL, Cz);
  tpack<<<dim3(16, 4, 4), 256, 0, stream>>>(xb, xm, xpH, xpL, Cz);

  for (int l = 0; l < Lz; l++) {
    pack_all<<<dim3(7184), 256, 0, stream>>>(
        wq + (size_t)l * Cz * Cz, wk + (size_t)l * Cz * Cz,
        wv + (size_t)l * Cz * Cz, wo + (size_t)l * Cz * Cz, bq + l * Cz,
        bk + l * Cz, bv + l * Cz, bo + l * Cz, erk + (size_t)l * NR * KCz,
        erv + (size_t)l * NR * KCz, fw1 + (size_t)l * FCz * Cz * 3,
        fw2 + (size_t)l * Cz * FCz * 3, qwH, qwL, pbias, ekH, ekL, evH, evL,
        w1H, w1L, w2H, w2L);
    mfma_gemm<1, 0><<<dim3(16, 12, 4), 256, 0, stream>>>(
        qwH, qwL, xpH, xpL, pbias, xm, nullptr, nullptr, 0, nullptr, nullptr,
        Qh, Ql, Kh, Kl, Vh, Vl, 1024, Cz, 0);
    attn_mfma<<<dim3(32, 16), 128, 0, stream>>>(Qh, Ql, Kh, Kl, Vh, Vl, xm,
                                                ekH, ekL, evH, evL, xpH, xpL);
    mfma_gemm<1, 1><<<dim3(16, 4, 4), 256, 0, stream>>>(
        qwH, qwL, xpH, xpL, pbias, xm, yb, nullptr, 0, nullptr, nullptr,
        nullptr, nullptr, nullptr, nullptr, nullptr, nullptr, 1024, Cz, 768);
    fused_ln<0><<<dim3(64, 4), 256, 0, stream>>>(
        xb, yb, nullptr, nullptr, g1 + l * Cz, b1 + l * Cz, xm, xpH, xpL);
    zero_halo<<<dim3((Bz * 2 * FCz + 255) / 256), 256, 0, stream>>>(hpH, hpL,
                                                                    FCz);
    mfma_gemm<3, 2><<<dim3(16, 16, 4), 256, 0, stream>>>(
        w1H, w1L, xpH, xpL, fb1 + l * FCz, xm, nullptr, nullptr, 0, hpH, hpL,
        nullptr, nullptr, nullptr, nullptr, nullptr, nullptr, FCz, Cz, 0);
    mfma_gemm<3, 3><<<dim3(16, 8, 4), 256, 0, stream>>>(
        w2H, w2L, hpH, hpL, nullptr, xm, yb, p1, 0, nullptr, nullptr, nullptr,
        nullptr, nullptr, nullptr, nullptr, nullptr, Cz, FCz, 0);
    fused_ln<1><<<dim3(64, 4), 256, 0, stream>>>(
        xb, yb, p1, fb2 + l * Cz, g2 + l * Cz, b2 + l * Cz, xm, xpH, xpL);
  }
  mask_out<<<dim3((ntot + 255) / 256), 256, 0, stream>>>(xb, xm,
                                                         (float*)d_out);
}